// Round 10
// baseline (228.773 us; speedup 1.0000x reference)
//
#include <hip/hip_runtime.h>
#include <hip/hip_fp16.h>
#include <math.h>

#define N_NODES 50000
#define N_EDGES 640000
#define HDIM    128
#define D_OUT   64
#define G_GRAPHS 500
#define EPSV    1e-5f
#define WPM     16384   // elements per packed 128x128 weight matrix

typedef __bf16 v8bf __attribute__((ext_vector_type(8)));
typedef float  f32x4 __attribute__((ext_vector_type(4)));

static __device__ __forceinline__ float bf_lo(unsigned u) {
    union { unsigned x; float f; } c; c.x = u << 16; return c.f;
}
static __device__ __forceinline__ float bf_hi(unsigned u) {
    union { unsigned x; float f; } c; c.x = u & 0xffff0000u; return c.f;
}

// ---------------------------------------------------------------------------
// Setup: zero cnt+pooled AND pack 7 f32 128x128 weights into bf16 MFMA
// B-fragment order with conv-softmax folded in:
//   m=0: pre_w   m=1,2: wc0[l]*gcn_w[l]  m=3,4: wc1[l]*sage_ws[l]
//   m=5,6: wc1[l]*sage_wn[l]
// ---------------------------------------------------------------------------
__global__ void setup_kernel(const float* __restrict__ pre_w,
                             const float* __restrict__ gcn_w,
                             const float* __restrict__ sws,
                             const float* __restrict__ swn,
                             const float* __restrict__ a_conv,
                             __bf16* __restrict__ Wp,
                             int* __restrict__ cnt,
                             float* __restrict__ pooled)
{
    int t = blockIdx.x * blockDim.x + threadIdx.x;
    if (t < N_NODES) cnt[t] = 0;
    if (t < G_GRAPHS * 128) pooled[t] = 0.f;
    if (t >= 7 * 2048) return;
    int m    = t >> 11;
    int r    = t & 2047;
    int lane = r & 63;
    int fb   = r >> 6;           // kc*8 + cb
    int kc   = fb >> 3;
    int cb   = fb & 7;
    const float* W = pre_w;
    float scale = 1.f;
    if (m > 0) {
        int type = (m - 1) >> 1;     // 0=gcn, 1=sage_ws, 2=sage_wn
        int l    = (m - 1) & 1;
        float c0 = a_conv[l * 2], c1 = a_conv[l * 2 + 1];
        float mx = fmaxf(c0, c1);
        float e0 = __expf(c0 - mx), e1 = __expf(c1 - mx);
        float wc0 = e0 / (e0 + e1);
        scale = (type == 0) ? wc0 : (1.f - wc0);
        W = (type == 0) ? gcn_w + (size_t)l * WPM
          : (type == 1) ? sws   + (size_t)l * WPM
                        : swn   + (size_t)l * WPM;
    }
    int k0  = kc * 32 + (lane >> 4) * 8;
    int col = cb * 16 + (lane & 15);
    __bf16* out = Wp + (size_t)m * WPM + ((size_t)fb * 64 + lane) * 8;
    #pragma unroll
    for (int i = 0; i < 8; i++)
        out[i] = (__bf16)(scale * W[(size_t)(k0 + i) * 128 + col]);
}

// ---------------------------------------------------------------------------
// Degrees
// ---------------------------------------------------------------------------
__global__ void count_deg_kernel(const int* __restrict__ dst, int* __restrict__ cnt, int E) {
    int i = blockIdx.x * blockDim.x + threadIdx.x;
    if (i < E) atomicAdd(&cnt[dst[i]], 1);
}

// ---------------------------------------------------------------------------
// Parallel exclusive scan: per-1024-chunk scan, then each scan_add block
// re-reduces the <=49 chunk totals itself (no separate middle kernel).
// ---------------------------------------------------------------------------
__global__ __launch_bounds__(1024) void scan_block_kernel(
    const int* __restrict__ cnt, int* __restrict__ ofs,
    int* __restrict__ btot, int n)
{
    __shared__ int wsum[16];
    const int tid  = threadIdx.x;
    const int lane = tid & 63;
    const int wid  = tid >> 6;
    int i = blockIdx.x * 1024 + tid;
    int v = (i < n) ? cnt[i] : 0;
    int x = v;
    #pragma unroll
    for (int o = 1; o < 64; o <<= 1) {
        int t = __shfl_up(x, o);
        if (lane >= o) x += t;
    }
    if (lane == 63) wsum[wid] = x;
    __syncthreads();
    if (wid == 0) {
        int y = (lane < 16) ? wsum[lane] : 0;
        #pragma unroll
        for (int o = 1; o < 16; o <<= 1) {
            int t = __shfl_up(y, o);
            if (lane >= o) y += t;
        }
        if (lane < 16) wsum[lane] = y;
    }
    __syncthreads();
    int wbase = (wid == 0) ? 0 : wsum[wid - 1];
    if (i < n) ofs[i] = wbase + x - v;      // chunk-local exclusive
    if (tid == 1023) btot[blockIdx.x] = wbase + x;
}

// scan finalize + header emit + fp16 dinv table (fused; computes its own
// chunk base from btot: block covers 256 contiguous idx -> single chunk).
__global__ __launch_bounds__(256) void scan_add_kernel(
    const int* __restrict__ ofs, int* __restrict__ cursor,
    const int* __restrict__ btot, const int* __restrict__ cnt,
    __half* __restrict__ dinvh, int4* __restrict__ hdr, int n, int nb)
{
    __shared__ int base_s;
    int c = blockIdx.x >> 2;                 // chunk index (4 blocks per 1024-chunk)
    if (threadIdx.x < 64) {
        int v = (threadIdx.x < (c < nb ? c : nb)) ? btot[threadIdx.x] : 0;
        #pragma unroll
        for (int o = 32; o; o >>= 1) v += __shfl_xor(v, o);
        if (threadIdx.x == 0) base_s = v;
    }
    __syncthreads();
    int i = blockIdx.x * 256 + threadIdx.x;
    if (i < n) {
        int o = ofs[i] + base_s;
        cursor[i] = o;
        int cc = cnt[i];
        float cf = (float)cc;
        float di = rsqrtf(cf + 1.0f);
        float rd = 1.0f / fmaxf(cf, 1.0f);
        dinvh[i] = __float2half(di);
        hdr[i] = make_int4(o, o + cc, __float_as_int(di), __float_as_int(rd));
    }
}

// ---------------------------------------------------------------------------
// CSR fill, 2-byte entries (src < 65536). Scattered-store writeback footprint
// halves again vs 4B packed entries.
// ---------------------------------------------------------------------------
__global__ void csr_fill_kernel(const int* __restrict__ src, const int* __restrict__ dst,
                                int* __restrict__ cursor,
                                unsigned short* __restrict__ csr, int E) {
    int e = blockIdx.x * blockDim.x + threadIdx.x;
    if (e < E) {
        int s = src[e];
        int d = dst[e];
        int pos = atomicAdd(&cursor[d], 1);
        csr[pos] = (unsigned short)s;
    }
}

// ---------------------------------------------------------------------------
// Pull-gather (bf16), channel-split: one wave per (node, row-half).
// 100k waves for TLP; per wave: 64 channels, 16 edges in flight
// (4 slots x 4 channels x 8B per lane). dinv[src] from hot fp16 table.
// ---------------------------------------------------------------------------
__global__ __launch_bounds__(256) void fused_gather_bf16(
    const __bf16* __restrict__ hb,
    const unsigned short* __restrict__ csr,
    const int4* __restrict__ hdr,
    const __half* __restrict__ dinvh,
    __bf16* __restrict__ aggGb,
    __bf16* __restrict__ meanb, int n)
{
    int wid  = (blockIdx.x * 256 + threadIdx.x) >> 6;   // global wave id
    int lane = threadIdx.x & 63;
    int d    = wid >> 1;
    int half = wid & 1;
    if (d >= n) return;
    int4 h4 = hdr[d];
    int beg = h4.x, end = h4.y;
    float did = __int_as_float(h4.z);
    float rd  = __int_as_float(h4.w);
    int q  = lane >> 4;                        // edge slot 0..3
    int c4 = half * 64 + (lane & 15) * 4;      // 4 channels (8B) per lane

    float aG[4] = {0, 0, 0, 0};
    float aS[4] = {0, 0, 0, 0};

    for (int p = beg; p < end; p += 16) {
        bool ok[4];
        int  s[4];
        #pragma unroll
        for (int k = 0; k < 4; k++) {
            int idx = p + 4 * k + q;
            ok[k] = idx < end;
            s[k] = csr[ok[k] ? idx : beg];
        }
        uint2 u[4];
        float ds[4];
        #pragma unroll
        for (int k = 0; k < 4; k++) {
            u[k]  = *(const uint2*)(hb + (size_t)s[k] * 128 + c4);
            ds[k] = __half2float(dinvh[s[k]]);
        }
        #pragma unroll
        for (int k = 0; k < 4; k++) {
            float wk = ok[k] ? ds[k] * did : 0.f;
            float mk = ok[k] ? 1.f : 0.f;
            float v[4] = { bf_lo(u[k].x), bf_hi(u[k].x), bf_lo(u[k].y), bf_hi(u[k].y) };
            #pragma unroll
            for (int j = 0; j < 4; j++) {
                aG[j] = fmaf(v[j], wk, aG[j]);
                aS[j] = fmaf(v[j], mk, aS[j]);
            }
        }
    }
    #pragma unroll
    for (int j = 0; j < 4; j++) {
        aG[j] += __shfl_xor(aG[j], 16);
        aG[j] += __shfl_xor(aG[j], 32);
        aS[j] += __shfl_xor(aS[j], 16);
        aS[j] += __shfl_xor(aS[j], 32);
    }
    if (q == 0) {
        uint2 ud = *(const uint2*)(hb + (size_t)d * 128 + c4);
        float vd[4] = { bf_lo(ud.x), bf_hi(ud.x), bf_lo(ud.y), bf_hi(ud.y) };
        float sl = did * did;
        union { __bf16 b[4]; uint2 u; } pg, pm;
        #pragma unroll
        for (int j = 0; j < 4; j++) {
            pg.b[j] = (__bf16)fmaf(vd[j], sl, aG[j]);
            pm.b[j] = (__bf16)(aS[j] * rd);
        }
        *(uint2*)(aggGb + (size_t)d * 128 + c4) = pg.u;
        *(uint2*)(meanb + (size_t)d * 128 + c4) = pm.u;
    }
}

// ---------------------------------------------------------------------------
// Pre-MLP: h_bf16 = x_f32 @ pre_w + pre_b, via MFMA; pre_w staged in LDS.
// ---------------------------------------------------------------------------
__global__ __launch_bounds__(256) void pre_gemm_mfma(
    const float* __restrict__ x, const __bf16* __restrict__ Wp0,
    const float* __restrict__ pre_b, __bf16* __restrict__ hb, int n)
{
    __shared__ __bf16 wlds[WPM];               // 32 KB
    const int tid  = threadIdx.x;
    const int w    = tid >> 6;
    const int lane = tid & 63;
    const int r0 = blockIdx.x * 64 + w * 16;
    int rl = r0 + (lane & 15);
    if (rl >= n) rl = n - 1;
    const int kg = lane >> 4;

    {
        uint4* lds4 = (uint4*)wlds;
        const uint4* g = (const uint4*)Wp0;
        #pragma unroll
        for (int it = 0; it < 8; it++)
            lds4[it * 256 + tid] = g[it * 256 + tid];
    }

    f32x4 acc[8];
    #pragma unroll
    for (int cb = 0; cb < 8; cb++) acc[cb] = (f32x4)(0.f);

    v8bf af[4];
    #pragma unroll
    for (int kc = 0; kc < 4; kc++) {
        const float* ap = x + (size_t)rl * 128 + kc * 32 + kg * 8;
        float4 a0 = *(const float4*)ap;
        float4 a1 = *(const float4*)(ap + 4);
        v8bf v;
        v[0] = (__bf16)a0.x; v[1] = (__bf16)a0.y;
        v[2] = (__bf16)a0.z; v[3] = (__bf16)a0.w;
        v[4] = (__bf16)a1.x; v[5] = (__bf16)a1.y;
        v[6] = (__bf16)a1.z; v[7] = (__bf16)a1.w;
        af[kc] = v;
    }
    __syncthreads();

    #pragma unroll
    for (int kc = 0; kc < 4; kc++) {
        #pragma unroll
        for (int cb = 0; cb < 8; cb++) {
            int bo = ((kc * 8 + cb) * 64 + lane) * 8;
            acc[cb] = __builtin_amdgcn_mfma_f32_16x16x32_bf16(
                af[kc], *(const v8bf*)&wlds[bo], acc[cb], 0, 0, 0);
        }
    }
    int cl = lane & 15;
    #pragma unroll
    for (int cb = 0; cb < 8; cb++) {
        float bias = pre_b[cb * 16 + cl];
        #pragma unroll
        for (int j = 0; j < 4; j++) {
            int r = r0 + kg * 4 + j;
            if (r < n) hb[(size_t)r * 128 + cb * 16 + cl] = (__bf16)(acc[cb][j] + bias);
        }
    }
}

// ---------------------------------------------------------------------------
// LAYER GEMM: single K=384 MFMA stream (conv softmax folded into weights),
// B-fragments staged in LDS (two 48KB phases). Then LN blend + act blend.
// ---------------------------------------------------------------------------
__global__ __launch_bounds__(256, 3) void layer_gemm_kernel(
    const __bf16* __restrict__ aggGb, const __bf16* __restrict__ hin,
    const __bf16* __restrict__ meanb,
    const __bf16* __restrict__ WpG, const __bf16* __restrict__ WpS,
    const __bf16* __restrict__ WpN,
    const float* __restrict__ gcn_b,
    const float* __restrict__ lng, const float* __restrict__ lnb,
    const float* __restrict__ anorm, const float* __restrict__ aact,
    const float* __restrict__ aconv,
    __bf16* __restrict__ hout, int n)
{
    __shared__ __bf16 wlds[3 * 16 * 64 * 8];   // 48 KB
    const int tid  = threadIdx.x;
    const int w    = tid >> 6;
    const int lane = tid & 63;
    const int r0 = blockIdx.x * 64 + w * 16;
    int rl = r0 + (lane & 15);
    if (rl >= n) rl = n - 1;
    const int kg = lane >> 4;

    v8bf af[12];
    #pragma unroll
    for (int kc = 0; kc < 4; kc++) {
        size_t ao = (size_t)rl * 128 + kc * 32 + kg * 8;
        af[kc]     = *(const v8bf*)(aggGb + ao);
        af[4 + kc] = *(const v8bf*)(hin   + ao);
        af[8 + kc] = *(const v8bf*)(meanb + ao);
    }

    f32x4 acc[8];
    #pragma unroll
    for (int cb = 0; cb < 8; cb++) acc[cb] = (f32x4)(0.f);

    uint4* lds4 = (uint4*)wlds;

    {
        const uint4* gG = (const uint4*)WpG;
        const uint4* gS = (const uint4*)WpS;
        const uint4* gN = (const uint4*)WpN;
        #pragma unroll
        for (int it = 0; it < 12; it++) {
            int idx = it * 256 + tid;
            int m = idx >> 10;
            int r = idx & 1023;
            const uint4* g = (m == 0) ? gG : (m == 1) ? gS : gN;
            lds4[idx] = g[r];
        }
    }
    __syncthreads();
    #pragma unroll
    for (int kc2 = 0; kc2 < 2; kc2++) {
        #pragma unroll
        for (int cb = 0; cb < 8; cb++) {
            int bo = ((kc2 * 8 + cb) * 64 + lane) * 8;
            acc[cb] = __builtin_amdgcn_mfma_f32_16x16x32_bf16(
                af[kc2], *(const v8bf*)&wlds[bo], acc[cb], 0, 0, 0);
            acc[cb] = __builtin_amdgcn_mfma_f32_16x16x32_bf16(
                af[4 + kc2], *(const v8bf*)&wlds[8192 + bo], acc[cb], 0, 0, 0);
            acc[cb] = __builtin_amdgcn_mfma_f32_16x16x32_bf16(
                af[8 + kc2], *(const v8bf*)&wlds[16384 + bo], acc[cb], 0, 0, 0);
        }
    }
    __syncthreads();

    {
        const uint4* gG = (const uint4*)WpG + 1024;
        const uint4* gS = (const uint4*)WpS + 1024;
        const uint4* gN = (const uint4*)WpN + 1024;
        #pragma unroll
        for (int it = 0; it < 12; it++) {
            int idx = it * 256 + tid;
            int m = idx >> 10;
            int r = idx & 1023;
            const uint4* g = (m == 0) ? gG : (m == 1) ? gS : gN;
            lds4[idx] = g[r];
        }
    }
    __syncthreads();
    #pragma unroll
    for (int kc2 = 0; kc2 < 2; kc2++) {
        #pragma unroll
        for (int cb = 0; cb < 8; cb++) {
            int bo = ((kc2 * 8 + cb) * 64 + lane) * 8;
            acc[cb] = __builtin_amdgcn_mfma_f32_16x16x32_bf16(
                af[2 + kc2], *(const v8bf*)&wlds[bo], acc[cb], 0, 0, 0);
            acc[cb] = __builtin_amdgcn_mfma_f32_16x16x32_bf16(
                af[6 + kc2], *(const v8bf*)&wlds[8192 + bo], acc[cb], 0, 0, 0);
            acc[cb] = __builtin_amdgcn_mfma_f32_16x16x32_bf16(
                af[10 + kc2], *(const v8bf*)&wlds[16384 + bo], acc[cb], 0, 0, 0);
        }
    }

    float c0 = aconv[0], c1 = aconv[1];
    float m = fmaxf(c0, c1);
    float e0 = __expf(c0 - m), e1 = __expf(c1 - m);
    float wc0 = e0 / (e0 + e1);
    float q0 = anorm[0], q1 = anorm[1];
    m = fmaxf(q0, q1);
    e0 = __expf(q0 - m); e1 = __expf(q1 - m);
    float wn0 = e0 / (e0 + e1), wn1 = 1.f - wn0;
    float a0 = aact[0], a1 = aact[1], a2 = aact[2];
    m = fmaxf(fmaxf(a0, a1), a2);
    float f0 = __expf(a0 - m), f1 = __expf(a1 - m), f2 = __expf(a2 - m);
    float fs = 1.f / (f0 + f1 + f2);
    float wa0 = f0 * fs, wa1 = f1 * fs, wa2 = f2 * fs;

    int cl = lane & 15;
    float gbF[8], lg[8], lb[8];
    #pragma unroll
    for (int cb = 0; cb < 8; cb++) {
        int c = cb * 16 + cl;
        gbF[cb] = wc0 * gcn_b[c]; lg[cb] = lng[c]; lb[cb] = lnb[c];
    }

    float s[4] = {0, 0, 0, 0}, s2[4] = {0, 0, 0, 0};
    #pragma unroll
    for (int cb = 0; cb < 8; cb++)
        #pragma unroll
        for (int j = 0; j < 4; j++) {
            float tv = acc[cb][j] + gbF[cb];
            acc[cb][j] = tv;
            s[j] += tv;
            s2[j] = fmaf(tv, tv, s2[j]);
        }
    #pragma unroll
    for (int o = 1; o < 16; o <<= 1)
        #pragma unroll
        for (int j = 0; j < 4; j++) {
            s[j]  += __shfl_xor(s[j], o);
            s2[j] += __shfl_xor(s2[j], o);
        }
    float mu[4], rs[4];
    #pragma unroll
    for (int j = 0; j < 4; j++) {
        mu[j] = s[j] * (1.f / 128.f);
        float var = s2[j] * (1.f / 128.f) - mu[j] * mu[j];
        rs[j] = rsqrtf(var + EPSV);
    }

    #pragma unroll
    for (int j = 0; j < 4; j++) {
        int r = r0 + kg * 4 + j;
        if (r >= n) continue;
        #pragma unroll
        for (int cb = 0; cb < 8; cb++) {
            float tv = acc[cb][j];
            float ln = (tv - mu[j]) * rs[j] * lg[cb] + lb[cb];
            float hv = wn0 * ln + wn1 * tv;
            float rl_ = fmaxf(hv, 0.f);
            float ex2 = __expf(2.f * hv);
            float th = 1.f - 2.f * __builtin_amdgcn_rcpf(ex2 + 1.f);
            float el = hv > 0.f ? hv : __expf(hv) - 1.f;
            float out = wa0 * rl_ + wa1 * th + wa2 * el;
            hout[(size_t)r * 128 + cb * 16 + cl] = (__bf16)out;
        }
    }
}

// ---------------------------------------------------------------------------
// Pooling: sum h1+h2 (bf16), batch sorted -> run-length accumulate.
// ---------------------------------------------------------------------------
__global__ __launch_bounds__(256) void pool_sum_kernel(
    const __bf16* __restrict__ h1, const __bf16* __restrict__ h2,
    const int* __restrict__ batch, float* __restrict__ pooled, int n)
{
    int c2  = (threadIdx.x & 63) * 2;
    int seg = threadIdx.x >> 6;
    int n0  = blockIdx.x * 128 + seg * 32;
    int g_cur = -1;
    float acc0 = 0.f, acc1 = 0.f;
    for (int i = 0; i < 32; i++) {
        int node = n0 + i;
        if (node >= n) break;
        int g = batch[node];
        if (g != g_cur) {
            if (g_cur >= 0) {
                atomicAdd(&pooled[(size_t)g_cur * 128 + c2], acc0);
                atomicAdd(&pooled[(size_t)g_cur * 128 + c2 + 1], acc1);
            }
            g_cur = g; acc0 = 0.f; acc1 = 0.f;
        }
        unsigned u1 = *(const unsigned*)(h1 + (size_t)node * 128 + c2);
        unsigned u2 = *(const unsigned*)(h2 + (size_t)node * 128 + c2);
        acc0 += bf_lo(u1) + bf_lo(u2);
        acc1 += bf_hi(u1) + bf_hi(u2);
    }
    if (g_cur >= 0) {
        atomicAdd(&pooled[(size_t)g_cur * 128 + c2], acc0);
        atomicAdd(&pooled[(size_t)g_cur * 128 + c2 + 1], acc1);
    }
}

__global__ __launch_bounds__(64) void post_gemm_kernel(
    const float* __restrict__ pooled, const float* __restrict__ W,
    const float* __restrict__ b, float* __restrict__ out)
{
    __shared__ float p_s[128];
    int g = blockIdx.x;
    int j = threadIdx.x;
    p_s[j]      = pooled[(size_t)g * 128 + j];
    p_s[j + 64] = pooled[(size_t)g * 128 + 64 + j];
    __syncthreads();
    float acc = b[j];
    #pragma unroll
    for (int k = 0; k < 128; k++)
        acc = fmaf(p_s[k], W[k * 64 + j], acc);
    out[(size_t)g * 64 + j] = acc;
}

// ---------------------------------------------------------------------------
extern "C" void kernel_launch(void* const* d_in, const int* in_sizes, int n_in,
                              void* d_out, int out_size, void* d_ws, size_t ws_size,
                              hipStream_t stream)
{
    const float* x       = (const float*)d_in[0];
    const int*   ei      = (const int*)d_in[1];
    const int*   batch   = (const int*)d_in[2];
    const float* pre_w   = (const float*)d_in[3];
    const float* pre_b   = (const float*)d_in[4];
    const float* post_w  = (const float*)d_in[5];
    const float* post_b  = (const float*)d_in[6];
    const float* gcn_w   = (const float*)d_in[7];
    const float* gcn_b   = (const float*)d_in[8];
    const float* sage_ws = (const float*)d_in[9];
    const float* sage_wn = (const float*)d_in[10];
    const float* ln_g    = (const float*)d_in[11];
    const float* ln_b    = (const float*)d_in[12];
    const float* a_conv  = (const float*)d_in[13];
    const float* a_norm  = (const float*)d_in[14];
    const float* a_act   = (const float*)d_in[15];

    const int* src = ei;
    const int* dst = ei + N_EDGES;

    char* wsp = (char*)d_ws;
    size_t off = 0;
    auto alloc = [&](size_t bytes) {
        char* p = wsp + off;
        off += (bytes + 255) & ~(size_t)255;
        return p;
    };
    const size_t NHB = (size_t)N_NODES * 128 * sizeof(__bf16);   // 12.8 MB
    __bf16*         hb0    = (__bf16*)alloc(NHB);
    __bf16*         h1b    = (__bf16*)alloc(NHB);
    __bf16*         h2b    = (__bf16*)alloc(NHB);
    __bf16*         aggGb  = (__bf16*)alloc(NHB);
    __bf16*         meanb  = (__bf16*)alloc(NHB);
    __bf16*         Wp     = (__bf16*)alloc((size_t)7 * WPM * sizeof(__bf16));
    __half*         dinvh  = (__half*)alloc(N_NODES * sizeof(__half));
    int*            cnt    = (int*)alloc(N_NODES * sizeof(int));
    int*            ofs    = (int*)alloc((N_NODES + 1) * sizeof(int));
    int*            cursor = (int*)alloc(N_NODES * sizeof(int));
    int4*           hdr    = (int4*)alloc((size_t)N_NODES * sizeof(int4));
    unsigned short* csr    = (unsigned short*)alloc((size_t)N_EDGES * sizeof(unsigned short));
    float*          pooled = (float*)alloc((size_t)G_GRAPHS * 128 * sizeof(float));
    int*            btot   = (int*)alloc(64 * sizeof(int));

    const int NB_SCAN = (N_NODES + 1023) / 1024;      // 49
    const int GEMM_BLOCKS = (N_NODES + 63) / 64;
    const int GATHER_BLOCKS = (2 * N_NODES + 3) / 4;  // 2 waves per node

    setup_kernel<<<(G_GRAPHS * 128 + 255) / 256, 256, 0, stream>>>(
        pre_w, gcn_w, sage_ws, sage_wn, a_conv, Wp, cnt, pooled);

    count_deg_kernel<<<(N_EDGES + 255) / 256, 256, 0, stream>>>(dst, cnt, N_EDGES);
    scan_block_kernel<<<NB_SCAN, 1024, 0, stream>>>(cnt, ofs, btot, N_NODES);
    scan_add_kernel<<<(N_NODES + 255) / 256, 256, 0, stream>>>(
        ofs, cursor, btot, cnt, dinvh, hdr, N_NODES, NB_SCAN);
    csr_fill_kernel<<<(N_EDGES + 255) / 256, 256, 0, stream>>>(
        src, dst, cursor, csr, N_EDGES);

    pre_gemm_mfma<<<GEMM_BLOCKS, 256, 0, stream>>>(x, Wp, pre_b, hb0, N_NODES);

    const __bf16* hin[2]  = { hb0, h1b };
    __bf16*       hout[2] = { h1b, h2b };
    for (int l = 0; l < 2; l++) {
        fused_gather_bf16<<<GATHER_BLOCKS, 256, 0, stream>>>(
            hin[l], csr, hdr, dinvh, aggGb, meanb, N_NODES);
        layer_gemm_kernel<<<GEMM_BLOCKS, 256, 0, stream>>>(
            aggGb, hin[l], meanb,
            Wp + (size_t)(1 + l) * WPM, Wp + (size_t)(3 + l) * WPM, Wp + (size_t)(5 + l) * WPM,
            gcn_b + l * 128, ln_g + l * 128, ln_b + l * 128,
            a_norm + l * 2, a_act + l * 3, a_conv + l * 2,
            hout[l], N_NODES);
    }

    pool_sum_kernel<<<(N_NODES + 127) / 128, 256, 0, stream>>>(h1b, h2b, batch, pooled, N_NODES);
    post_gemm_kernel<<<G_GRAPHS, 64, 0, stream>>>(pooled, post_w, post_b, (float*)d_out);
}

// Round 11
// 207.965 us; speedup vs baseline: 1.1001x; 1.1001x over previous
//
#include <hip/hip_runtime.h>
#include <hip/hip_fp16.h>
#include <math.h>

#define N_NODES 50000
#define N_EDGES 640000
#define HDIM    128
#define D_OUT   64
#define G_GRAPHS 500
#define EPSV    1e-5f
#define WPM     16384   // elements per packed 128x128 weight matrix

typedef __bf16 v8bf __attribute__((ext_vector_type(8)));
typedef float  f32x4 __attribute__((ext_vector_type(4)));

static __device__ __forceinline__ float bf_lo(unsigned u) {
    union { unsigned x; float f; } c; c.x = u << 16; return c.f;
}
static __device__ __forceinline__ float bf_hi(unsigned u) {
    union { unsigned x; float f; } c; c.x = u & 0xffff0000u; return c.f;
}

// ---------------------------------------------------------------------------
// Setup: zero cnt+pooled AND pack 7 f32 128x128 weights into bf16 MFMA
// B-fragment order with conv-softmax folded in:
//   m=0: pre_w   m=1,2: wc0[l]*gcn_w[l]  m=3,4: wc1[l]*sage_ws[l]
//   m=5,6: wc1[l]*sage_wn[l]
// ---------------------------------------------------------------------------
__global__ void setup_kernel(const float* __restrict__ pre_w,
                             const float* __restrict__ gcn_w,
                             const float* __restrict__ sws,
                             const float* __restrict__ swn,
                             const float* __restrict__ a_conv,
                             __bf16* __restrict__ Wp,
                             int* __restrict__ cnt,
                             float* __restrict__ pooled)
{
    int t = blockIdx.x * blockDim.x + threadIdx.x;
    if (t < N_NODES) cnt[t] = 0;
    if (t < G_GRAPHS * 128) pooled[t] = 0.f;
    if (t >= 7 * 2048) return;
    int m    = t >> 11;
    int r    = t & 2047;
    int lane = r & 63;
    int fb   = r >> 6;           // kc*8 + cb
    int kc   = fb >> 3;
    int cb   = fb & 7;
    const float* W = pre_w;
    float scale = 1.f;
    if (m > 0) {
        int type = (m - 1) >> 1;     // 0=gcn, 1=sage_ws, 2=sage_wn
        int l    = (m - 1) & 1;
        float c0 = a_conv[l * 2], c1 = a_conv[l * 2 + 1];
        float mx = fmaxf(c0, c1);
        float e0 = __expf(c0 - mx), e1 = __expf(c1 - mx);
        float wc0 = e0 / (e0 + e1);
        scale = (type == 0) ? wc0 : (1.f - wc0);
        W = (type == 0) ? gcn_w + (size_t)l * WPM
          : (type == 1) ? sws   + (size_t)l * WPM
                        : swn   + (size_t)l * WPM;
    }
    int k0  = kc * 32 + (lane >> 4) * 8;
    int col = cb * 16 + (lane & 15);
    __bf16* out = Wp + (size_t)m * WPM + ((size_t)fb * 64 + lane) * 8;
    #pragma unroll
    for (int i = 0; i < 8; i++)
        out[i] = (__bf16)(scale * W[(size_t)(k0 + i) * 128 + col]);
}

// ---------------------------------------------------------------------------
// Degrees
// ---------------------------------------------------------------------------
__global__ void count_deg_kernel(const int* __restrict__ dst, int* __restrict__ cnt, int E) {
    int i = blockIdx.x * blockDim.x + threadIdx.x;
    if (i < E) atomicAdd(&cnt[dst[i]], 1);
}

// ---------------------------------------------------------------------------
// Parallel exclusive scan: per-1024-chunk scan, then scan_add blocks
// re-reduce the <=49 chunk totals themselves.
// ---------------------------------------------------------------------------
__global__ __launch_bounds__(1024) void scan_block_kernel(
    const int* __restrict__ cnt, int* __restrict__ ofs,
    int* __restrict__ btot, int n)
{
    __shared__ int wsum[16];
    const int tid  = threadIdx.x;
    const int lane = tid & 63;
    const int wid  = tid >> 6;
    int i = blockIdx.x * 1024 + tid;
    int v = (i < n) ? cnt[i] : 0;
    int x = v;
    #pragma unroll
    for (int o = 1; o < 64; o <<= 1) {
        int t = __shfl_up(x, o);
        if (lane >= o) x += t;
    }
    if (lane == 63) wsum[wid] = x;
    __syncthreads();
    if (wid == 0) {
        int y = (lane < 16) ? wsum[lane] : 0;
        #pragma unroll
        for (int o = 1; o < 16; o <<= 1) {
            int t = __shfl_up(y, o);
            if (lane >= o) y += t;
        }
        if (lane < 16) wsum[lane] = y;
    }
    __syncthreads();
    int wbase = (wid == 0) ? 0 : wsum[wid - 1];
    if (i < n) ofs[i] = wbase + x - v;      // chunk-local exclusive
    if (tid == 1023) btot[blockIdx.x] = wbase + x;
}

// scan finalize + header emit + fp16 dinv table (fused)
__global__ __launch_bounds__(256) void scan_add_kernel(
    const int* __restrict__ ofs, int* __restrict__ cursor,
    const int* __restrict__ btot, const int* __restrict__ cnt,
    __half* __restrict__ dinvh, int4* __restrict__ hdr, int n, int nb)
{
    __shared__ int base_s;
    int c = blockIdx.x >> 2;                 // chunk index (4 blocks per 1024-chunk)
    if (threadIdx.x < 64) {
        int v = (threadIdx.x < (c < nb ? c : nb)) ? btot[threadIdx.x] : 0;
        #pragma unroll
        for (int o = 32; o; o >>= 1) v += __shfl_xor(v, o);
        if (threadIdx.x == 0) base_s = v;
    }
    __syncthreads();
    int i = blockIdx.x * 256 + threadIdx.x;
    if (i < n) {
        int o = ofs[i] + base_s;
        cursor[i] = o;
        int cc = cnt[i];
        float cf = (float)cc;
        float di = rsqrtf(cf + 1.0f);
        float rd = 1.0f / fmaxf(cf, 1.0f);
        dinvh[i] = __float2half(di);
        hdr[i] = make_int4(o, o + cc, __float_as_int(di), __float_as_int(rd));
    }
}

// ---------------------------------------------------------------------------
// CSR fill, 2-byte entries (src < 65536) — minimal scattered-store writeback.
// ---------------------------------------------------------------------------
__global__ void csr_fill_kernel(const int* __restrict__ src, const int* __restrict__ dst,
                                int* __restrict__ cursor,
                                unsigned short* __restrict__ csr, int E) {
    int e = blockIdx.x * blockDim.x + threadIdx.x;
    if (e < E) {
        int s = src[e];
        int d = dst[e];
        int pos = atomicAdd(&cursor[d], 1);
        csr[pos] = (unsigned short)s;
    }
}

// ---------------------------------------------------------------------------
// Pull-gather (bf16): one wave per dst node (R9 shape — known-good), packed
// header, 2-byte csr entries + fp16 dinv table, 16 edges in flight
// (4 slots x 16 lanes x 16B per row).
// ---------------------------------------------------------------------------
__global__ __launch_bounds__(256) void fused_gather_bf16(
    const __bf16* __restrict__ hb,
    const unsigned short* __restrict__ csr,
    const int4* __restrict__ hdr,
    const __half* __restrict__ dinvh,
    __bf16* __restrict__ aggGb,
    __bf16* __restrict__ meanb, int n)
{
    int w = threadIdx.x >> 6;
    int lane = threadIdx.x & 63;
    int d = blockIdx.x * 4 + w;
    if (d >= n) return;
    int4 h4 = hdr[d];
    int beg = h4.x, end = h4.y;
    float did = __int_as_float(h4.z);
    float rd  = __int_as_float(h4.w);
    int q  = lane >> 4;
    int c8 = (lane & 15) * 8;

    float aG[8] = {0, 0, 0, 0, 0, 0, 0, 0};
    float aS[8] = {0, 0, 0, 0, 0, 0, 0, 0};

    for (int p = beg; p < end; p += 16) {
        bool ok[4];
        int  s[4];
        #pragma unroll
        for (int k = 0; k < 4; k++) {
            int idx = p + 4 * k + q;
            ok[k] = idx < end;
            s[k] = csr[ok[k] ? idx : beg];
        }
        uint4 u[4];
        float ds[4];
        #pragma unroll
        for (int k = 0; k < 4; k++) {
            u[k]  = *(const uint4*)(hb + (size_t)s[k] * 128 + c8);
            ds[k] = __half2float(dinvh[s[k]]);
        }
        #pragma unroll
        for (int k = 0; k < 4; k++) {
            float wk = ok[k] ? ds[k] * did : 0.f;
            float mk = ok[k] ? 1.f : 0.f;
            float v[8] = { bf_lo(u[k].x), bf_hi(u[k].x), bf_lo(u[k].y), bf_hi(u[k].y),
                           bf_lo(u[k].z), bf_hi(u[k].z), bf_lo(u[k].w), bf_hi(u[k].w) };
            #pragma unroll
            for (int j = 0; j < 8; j++) {
                aG[j] = fmaf(v[j], wk, aG[j]);
                aS[j] = fmaf(v[j], mk, aS[j]);
            }
        }
    }
    #pragma unroll
    for (int j = 0; j < 8; j++) {
        aG[j] += __shfl_xor(aG[j], 16);
        aG[j] += __shfl_xor(aG[j], 32);
        aS[j] += __shfl_xor(aS[j], 16);
        aS[j] += __shfl_xor(aS[j], 32);
    }
    if (q == 0) {
        uint4 ud = *(const uint4*)(hb + (size_t)d * 128 + c8);
        float vd[8] = { bf_lo(ud.x), bf_hi(ud.x), bf_lo(ud.y), bf_hi(ud.y),
                        bf_lo(ud.z), bf_hi(ud.z), bf_lo(ud.w), bf_hi(ud.w) };
        float sl = did * did;
        union { __bf16 b[8]; uint4 u; } pg, pm;
        #pragma unroll
        for (int j = 0; j < 8; j++) {
            pg.b[j] = (__bf16)fmaf(vd[j], sl, aG[j]);
            pm.b[j] = (__bf16)(aS[j] * rd);
        }
        *(uint4*)(aggGb + (size_t)d * 128 + c8) = pg.u;
        *(uint4*)(meanb + (size_t)d * 128 + c8) = pm.u;
    }
}

// ---------------------------------------------------------------------------
// Pre-MLP: h_bf16 = x_f32 @ pre_w + pre_b, via MFMA; pre_w staged in LDS.
// ---------------------------------------------------------------------------
__global__ __launch_bounds__(256) void pre_gemm_mfma(
    const float* __restrict__ x, const __bf16* __restrict__ Wp0,
    const float* __restrict__ pre_b, __bf16* __restrict__ hb, int n)
{
    __shared__ __bf16 wlds[WPM];               // 32 KB
    const int tid  = threadIdx.x;
    const int w    = tid >> 6;
    const int lane = tid & 63;
    const int r0 = blockIdx.x * 64 + w * 16;
    int rl = r0 + (lane & 15);
    if (rl >= n) rl = n - 1;
    const int kg = lane >> 4;

    {
        uint4* lds4 = (uint4*)wlds;
        const uint4* g = (const uint4*)Wp0;
        #pragma unroll
        for (int it = 0; it < 8; it++)
            lds4[it * 256 + tid] = g[it * 256 + tid];
    }

    f32x4 acc[8];
    #pragma unroll
    for (int cb = 0; cb < 8; cb++) acc[cb] = (f32x4)(0.f);

    v8bf af[4];
    #pragma unroll
    for (int kc = 0; kc < 4; kc++) {
        const float* ap = x + (size_t)rl * 128 + kc * 32 + kg * 8;
        float4 a0 = *(const float4*)ap;
        float4 a1 = *(const float4*)(ap + 4);
        v8bf v;
        v[0] = (__bf16)a0.x; v[1] = (__bf16)a0.y;
        v[2] = (__bf16)a0.z; v[3] = (__bf16)a0.w;
        v[4] = (__bf16)a1.x; v[5] = (__bf16)a1.y;
        v[6] = (__bf16)a1.z; v[7] = (__bf16)a1.w;
        af[kc] = v;
    }
    __syncthreads();

    #pragma unroll
    for (int kc = 0; kc < 4; kc++) {
        #pragma unroll
        for (int cb = 0; cb < 8; cb++) {
            int bo = ((kc * 8 + cb) * 64 + lane) * 8;
            acc[cb] = __builtin_amdgcn_mfma_f32_16x16x32_bf16(
                af[kc], *(const v8bf*)&wlds[bo], acc[cb], 0, 0, 0);
        }
    }
    int cl = lane & 15;
    #pragma unroll
    for (int cb = 0; cb < 8; cb++) {
        float bias = pre_b[cb * 16 + cl];
        #pragma unroll
        for (int j = 0; j < 4; j++) {
            int r = r0 + kg * 4 + j;
            if (r < n) hb[(size_t)r * 128 + cb * 16 + cl] = (__bf16)(acc[cb][j] + bias);
        }
    }
}

// ---------------------------------------------------------------------------
// LAYER GEMM: single K=384 MFMA stream (conv softmax folded into weights),
// B-fragments staged in LDS (two 48KB phases). Then LN blend + act blend.
// ---------------------------------------------------------------------------
__global__ __launch_bounds__(256, 3) void layer_gemm_kernel(
    const __bf16* __restrict__ aggGb, const __bf16* __restrict__ hin,
    const __bf16* __restrict__ meanb,
    const __bf16* __restrict__ WpG, const __bf16* __restrict__ WpS,
    const __bf16* __restrict__ WpN,
    const float* __restrict__ gcn_b,
    const float* __restrict__ lng, const float* __restrict__ lnb,
    const float* __restrict__ anorm, const float* __restrict__ aact,
    const float* __restrict__ aconv,
    __bf16* __restrict__ hout, int n)
{
    __shared__ __bf16 wlds[3 * 16 * 64 * 8];   // 48 KB
    const int tid  = threadIdx.x;
    const int w    = tid >> 6;
    const int lane = tid & 63;
    const int r0 = blockIdx.x * 64 + w * 16;
    int rl = r0 + (lane & 15);
    if (rl >= n) rl = n - 1;
    const int kg = lane >> 4;

    v8bf af[12];
    #pragma unroll
    for (int kc = 0; kc < 4; kc++) {
        size_t ao = (size_t)rl * 128 + kc * 32 + kg * 8;
        af[kc]     = *(const v8bf*)(aggGb + ao);
        af[4 + kc] = *(const v8bf*)(hin   + ao);
        af[8 + kc] = *(const v8bf*)(meanb + ao);
    }

    f32x4 acc[8];
    #pragma unroll
    for (int cb = 0; cb < 8; cb++) acc[cb] = (f32x4)(0.f);

    uint4* lds4 = (uint4*)wlds;

    {
        const uint4* gG = (const uint4*)WpG;
        const uint4* gS = (const uint4*)WpS;
        const uint4* gN = (const uint4*)WpN;
        #pragma unroll
        for (int it = 0; it < 12; it++) {
            int idx = it * 256 + tid;
            int m = idx >> 10;
            int r = idx & 1023;
            const uint4* g = (m == 0) ? gG : (m == 1) ? gS : gN;
            lds4[idx] = g[r];
        }
    }
    __syncthreads();
    #pragma unroll
    for (int kc2 = 0; kc2 < 2; kc2++) {
        #pragma unroll
        for (int cb = 0; cb < 8; cb++) {
            int bo = ((kc2 * 8 + cb) * 64 + lane) * 8;
            acc[cb] = __builtin_amdgcn_mfma_f32_16x16x32_bf16(
                af[kc2], *(const v8bf*)&wlds[bo], acc[cb], 0, 0, 0);
            acc[cb] = __builtin_amdgcn_mfma_f32_16x16x32_bf16(
                af[4 + kc2], *(const v8bf*)&wlds[8192 + bo], acc[cb], 0, 0, 0);
            acc[cb] = __builtin_amdgcn_mfma_f32_16x16x32_bf16(
                af[8 + kc2], *(const v8bf*)&wlds[16384 + bo], acc[cb], 0, 0, 0);
        }
    }
    __syncthreads();

    {
        const uint4* gG = (const uint4*)WpG + 1024;
        const uint4* gS = (const uint4*)WpS + 1024;
        const uint4* gN = (const uint4*)WpN + 1024;
        #pragma unroll
        for (int it = 0; it < 12; it++) {
            int idx = it * 256 + tid;
            int m = idx >> 10;
            int r = idx & 1023;
            const uint4* g = (m == 0) ? gG : (m == 1) ? gS : gN;
            lds4[idx] = g[r];
        }
    }
    __syncthreads();
    #pragma unroll
    for (int kc2 = 0; kc2 < 2; kc2++) {
        #pragma unroll
        for (int cb = 0; cb < 8; cb++) {
            int bo = ((kc2 * 8 + cb) * 64 + lane) * 8;
            acc[cb] = __builtin_amdgcn_mfma_f32_16x16x32_bf16(
                af[2 + kc2], *(const v8bf*)&wlds[bo], acc[cb], 0, 0, 0);
            acc[cb] = __builtin_amdgcn_mfma_f32_16x16x32_bf16(
                af[6 + kc2], *(const v8bf*)&wlds[8192 + bo], acc[cb], 0, 0, 0);
            acc[cb] = __builtin_amdgcn_mfma_f32_16x16x32_bf16(
                af[10 + kc2], *(const v8bf*)&wlds[16384 + bo], acc[cb], 0, 0, 0);
        }
    }

    float c0 = aconv[0], c1 = aconv[1];
    float m = fmaxf(c0, c1);
    float e0 = __expf(c0 - m), e1 = __expf(c1 - m);
    float wc0 = e0 / (e0 + e1);
    float q0 = anorm[0], q1 = anorm[1];
    m = fmaxf(q0, q1);
    e0 = __expf(q0 - m); e1 = __expf(q1 - m);
    float wn0 = e0 / (e0 + e1), wn1 = 1.f - wn0;
    float a0 = aact[0], a1 = aact[1], a2 = aact[2];
    m = fmaxf(fmaxf(a0, a1), a2);
    float f0 = __expf(a0 - m), f1 = __expf(a1 - m), f2 = __expf(a2 - m);
    float fs = 1.f / (f0 + f1 + f2);
    float wa0 = f0 * fs, wa1 = f1 * fs, wa2 = f2 * fs;

    int cl = lane & 15;
    float gbF[8], lg[8], lb[8];
    #pragma unroll
    for (int cb = 0; cb < 8; cb++) {
        int c = cb * 16 + cl;
        gbF[cb] = wc0 * gcn_b[c]; lg[cb] = lng[c]; lb[cb] = lnb[c];
    }

    float s[4] = {0, 0, 0, 0}, s2[4] = {0, 0, 0, 0};
    #pragma unroll
    for (int cb = 0; cb < 8; cb++)
        #pragma unroll
        for (int j = 0; j < 4; j++) {
            float tv = acc[cb][j] + gbF[cb];
            acc[cb][j] = tv;
            s[j] += tv;
            s2[j] = fmaf(tv, tv, s2[j]);
        }
    #pragma unroll
    for (int o = 1; o < 16; o <<= 1)
        #pragma unroll
        for (int j = 0; j < 4; j++) {
            s[j]  += __shfl_xor(s[j], o);
            s2[j] += __shfl_xor(s2[j], o);
        }
    float mu[4], rs[4];
    #pragma unroll
    for (int j = 0; j < 4; j++) {
        mu[j] = s[j] * (1.f / 128.f);
        float var = s2[j] * (1.f / 128.f) - mu[j] * mu[j];
        rs[j] = rsqrtf(var + EPSV);
    }

    #pragma unroll
    for (int j = 0; j < 4; j++) {
        int r = r0 + kg * 4 + j;
        if (r >= n) continue;
        #pragma unroll
        for (int cb = 0; cb < 8; cb++) {
            float tv = acc[cb][j];
            float ln = (tv - mu[j]) * rs[j] * lg[cb] + lb[cb];
            float hv = wn0 * ln + wn1 * tv;
            float rl_ = fmaxf(hv, 0.f);
            float ex2 = __expf(2.f * hv);
            float th = 1.f - 2.f * __builtin_amdgcn_rcpf(ex2 + 1.f);
            float el = hv > 0.f ? hv : __expf(hv) - 1.f;
            float out = wa0 * rl_ + wa1 * th + wa2 * el;
            hout[(size_t)r * 128 + cb * 16 + cl] = (__bf16)out;
        }
    }
}

// ---------------------------------------------------------------------------
// Pooling: sum h1+h2 (bf16), batch sorted -> run-length accumulate.
// ---------------------------------------------------------------------------
__global__ __launch_bounds__(256) void pool_sum_kernel(
    const __bf16* __restrict__ h1, const __bf16* __restrict__ h2,
    const int* __restrict__ batch, float* __restrict__ pooled, int n)
{
    int c2  = (threadIdx.x & 63) * 2;
    int seg = threadIdx.x >> 6;
    int n0  = blockIdx.x * 128 + seg * 32;
    int g_cur = -1;
    float acc0 = 0.f, acc1 = 0.f;
    for (int i = 0; i < 32; i++) {
        int node = n0 + i;
        if (node >= n) break;
        int g = batch[node];
        if (g != g_cur) {
            if (g_cur >= 0) {
                atomicAdd(&pooled[(size_t)g_cur * 128 + c2], acc0);
                atomicAdd(&pooled[(size_t)g_cur * 128 + c2 + 1], acc1);
            }
            g_cur = g; acc0 = 0.f; acc1 = 0.f;
        }
        unsigned u1 = *(const unsigned*)(h1 + (size_t)node * 128 + c2);
        unsigned u2 = *(const unsigned*)(h2 + (size_t)node * 128 + c2);
        acc0 += bf_lo(u1) + bf_lo(u2);
        acc1 += bf_hi(u1) + bf_hi(u2);
    }
    if (g_cur >= 0) {
        atomicAdd(&pooled[(size_t)g_cur * 128 + c2], acc0);
        atomicAdd(&pooled[(size_t)g_cur * 128 + c2 + 1], acc1);
    }
}

__global__ __launch_bounds__(64) void post_gemm_kernel(
    const float* __restrict__ pooled, const float* __restrict__ W,
    const float* __restrict__ b, float* __restrict__ out)
{
    __shared__ float p_s[128];
    int g = blockIdx.x;
    int j = threadIdx.x;
    p_s[j]      = pooled[(size_t)g * 128 + j];
    p_s[j + 64] = pooled[(size_t)g * 128 + 64 + j];
    __syncthreads();
    float acc = b[j];
    #pragma unroll
    for (int k = 0; k < 128; k++)
        acc = fmaf(p_s[k], W[k * 64 + j], acc);
    out[(size_t)g * 64 + j] = acc;
}

// ---------------------------------------------------------------------------
extern "C" void kernel_launch(void* const* d_in, const int* in_sizes, int n_in,
                              void* d_out, int out_size, void* d_ws, size_t ws_size,
                              hipStream_t stream)
{
    const float* x       = (const float*)d_in[0];
    const int*   ei      = (const int*)d_in[1];
    const int*   batch   = (const int*)d_in[2];
    const float* pre_w   = (const float*)d_in[3];
    const float* pre_b   = (const float*)d_in[4];
    const float* post_w  = (const float*)d_in[5];
    const float* post_b  = (const float*)d_in[6];
    const float* gcn_w   = (const float*)d_in[7];
    const float* gcn_b   = (const float*)d_in[8];
    const float* sage_ws = (const float*)d_in[9];
    const float* sage_wn = (const float*)d_in[10];
    const float* ln_g    = (const float*)d_in[11];
    const float* ln_b    = (const float*)d_in[12];
    const float* a_conv  = (const float*)d_in[13];
    const float* a_norm  = (const float*)d_in[14];
    const float* a_act   = (const float*)d_in[15];

    const int* src = ei;
    const int* dst = ei + N_EDGES;

    char* wsp = (char*)d_ws;
    size_t off = 0;
    auto alloc = [&](size_t bytes) {
        char* p = wsp + off;
        off += (bytes + 255) & ~(size_t)255;
        return p;
    };
    const size_t NHB = (size_t)N_NODES * 128 * sizeof(__bf16);   // 12.8 MB
    __bf16*         hb0    = (__bf16*)alloc(NHB);
    __bf16*         h1b    = (__bf16*)alloc(NHB);
    __bf16*         h2b    = (__bf16*)alloc(NHB);
    __bf16*         aggGb  = (__bf16*)alloc(NHB);
    __bf16*         meanb  = (__bf16*)alloc(NHB);
    __bf16*         Wp     = (__bf16*)alloc((size_t)7 * WPM * sizeof(__bf16));
    __half*         dinvh  = (__half*)alloc(N_NODES * sizeof(__half));
    int*            cnt    = (int*)alloc(N_NODES * sizeof(int));
    int*            ofs    = (int*)alloc((N_NODES + 1) * sizeof(int));
    int*            cursor = (int*)alloc(N_NODES * sizeof(int));
    int4*           hdr    = (int4*)alloc((size_t)N_NODES * sizeof(int4));
    unsigned short* csr    = (unsigned short*)alloc((size_t)N_EDGES * sizeof(unsigned short));
    float*          pooled = (float*)alloc((size_t)G_GRAPHS * 128 * sizeof(float));
    int*            btot   = (int*)alloc(64 * sizeof(int));

    const int NB_SCAN = (N_NODES + 1023) / 1024;      // 49
    const int GEMM_BLOCKS = (N_NODES + 63) / 64;
    const int GATHER_BLOCKS = (N_NODES + 3) / 4;

    setup_kernel<<<(G_GRAPHS * 128 + 255) / 256, 256, 0, stream>>>(
        pre_w, gcn_w, sage_ws, sage_wn, a_conv, Wp, cnt, pooled);

    count_deg_kernel<<<(N_EDGES + 255) / 256, 256, 0, stream>>>(dst, cnt, N_EDGES);
    scan_block_kernel<<<NB_SCAN, 1024, 0, stream>>>(cnt, ofs, btot, N_NODES);
    scan_add_kernel<<<(N_NODES + 255) / 256, 256, 0, stream>>>(
        ofs, cursor, btot, cnt, dinvh, hdr, N_NODES, NB_SCAN);
    csr_fill_kernel<<<(N_EDGES + 255) / 256, 256, 0, stream>>>(
        src, dst, cursor, csr, N_EDGES);

    pre_gemm_mfma<<<GEMM_BLOCKS, 256, 0, stream>>>(x, Wp, pre_b, hb0, N_NODES);

    const __bf16* hin[2]  = { hb0, h1b };
    __bf16*       hout[2] = { h1b, h2b };
    for (int l = 0; l < 2; l++) {
        fused_gather_bf16<<<GATHER_BLOCKS, 256, 0, stream>>>(
            hin[l], csr, hdr, dinvh, aggGb, meanb, N_NODES);
        layer_gemm_kernel<<<GEMM_BLOCKS, 256, 0, stream>>>(
            aggGb, hin[l], meanb,
            Wp + (size_t)(1 + l) * WPM, Wp + (size_t)(3 + l) * WPM, Wp + (size_t)(5 + l) * WPM,
            gcn_b + l * 128, ln_g + l * 128, ln_b + l * 128,
            a_norm + l * 2, a_act + l * 3, a_conv + l * 2,
            hout[l], N_NODES);
    }

    pool_sum_kernel<<<(N_NODES + 127) / 128, 256, 0, stream>>>(h1b, h2b, batch, pooled, N_NODES);
    post_gemm_kernel<<<G_GRAPHS, 64, 0, stream>>>(pooled, post_w, post_b, (float*)d_out);
}

// Round 12
// 184.535 us; speedup vs baseline: 1.2397x; 1.1270x over previous
//
#include <hip/hip_runtime.h>
#include <hip/hip_fp16.h>
#include <math.h>

#define N_NODES 50000
#define N_EDGES 640000
#define HDIM    128
#define D_OUT   64
#define G_GRAPHS 500
#define EPSV    1e-5f
#define WPM     16384   // elements per packed 128x128 weight matrix
#define CAP     64      // bucket capacity (mean deg 12.8, P(deg>=64)~1e-24)
#define SENT    N_NODES // sentinel src id -> zero row, dinvh[SENT]=0

typedef __bf16 v8bf __attribute__((ext_vector_type(8)));
typedef float  f32x4 __attribute__((ext_vector_type(4)));

static __device__ __forceinline__ float bf_lo(unsigned u) {
    union { unsigned x; float f; } c; c.x = u << 16; return c.f;
}
static __device__ __forceinline__ float bf_hi(unsigned u) {
    union { unsigned x; float f; } c; c.x = u & 0xffff0000u; return c.f;
}

// ---------------------------------------------------------------------------
// Setup: zero cnt+pooled, sentinel-fill csr buckets, zero phantom h rows,
// AND pack 7 f32 128x128 weights into bf16 MFMA B-fragment order with
// conv-softmax folded in:
//   m=0: pre_w   m=1,2: wc0[l]*gcn_w[l]  m=3,4: wc1[l]*sage_ws[l]
//   m=5,6: wc1[l]*sage_wn[l]
// Grid: 1568 blocks x 256 (covers 400k uint4 sentinel stores).
// ---------------------------------------------------------------------------
__global__ void setup_kernel(const float* __restrict__ pre_w,
                             const float* __restrict__ gcn_w,
                             const float* __restrict__ sws,
                             const float* __restrict__ swn,
                             const float* __restrict__ a_conv,
                             __bf16* __restrict__ Wp,
                             int* __restrict__ cnt,
                             float* __restrict__ pooled,
                             uint4* __restrict__ csr4,
                             uint4* __restrict__ hrow0,
                             uint4* __restrict__ hrow1)
{
    int t = blockIdx.x * blockDim.x + threadIdx.x;
    // sentinel fill: N_NODES*CAP u16 entries = 400000 uint4
    const unsigned sv = ((unsigned)SENT << 16) | (unsigned)SENT;  // 0xC350C350
    if (t < N_NODES * CAP / 8) csr4[t] = make_uint4(sv, sv, sv, sv);
    if (t < N_NODES) cnt[t] = 0;
    if (t < G_GRAPHS * 128) pooled[t] = 0.f;
    if (t < 16) {  // zero phantom row N of hb0 and h1b (256B each)
        hrow0[t] = make_uint4(0, 0, 0, 0);
        hrow1[t] = make_uint4(0, 0, 0, 0);
    }
    if (t >= 7 * 2048) return;
    int m    = t >> 11;
    int r    = t & 2047;
    int lane = r & 63;
    int fb   = r >> 6;           // kc*8 + cb
    int kc   = fb >> 3;
    int cb   = fb & 7;
    const float* W = pre_w;
    float scale = 1.f;
    if (m > 0) {
        int type = (m - 1) >> 1;     // 0=gcn, 1=sage_ws, 2=sage_wn
        int l    = (m - 1) & 1;
        float c0 = a_conv[l * 2], c1 = a_conv[l * 2 + 1];
        float mx = fmaxf(c0, c1);
        float e0 = __expf(c0 - mx), e1 = __expf(c1 - mx);
        float wc0 = e0 / (e0 + e1);
        scale = (type == 0) ? wc0 : (1.f - wc0);
        W = (type == 0) ? gcn_w + (size_t)l * WPM
          : (type == 1) ? sws   + (size_t)l * WPM
                        : swn   + (size_t)l * WPM;
    }
    int k0  = kc * 32 + (lane >> 4) * 8;
    int col = cb * 16 + (lane & 15);
    __bf16* out = Wp + (size_t)m * WPM + ((size_t)fb * 64 + lane) * 8;
    #pragma unroll
    for (int i = 0; i < 8; i++)
        out[i] = (__bf16)(scale * W[(size_t)(k0 + i) * 128 + col]);
}

// ---------------------------------------------------------------------------
// Direct-bucket CSR fill: no counting pass, no scan. 2-byte entries.
// ---------------------------------------------------------------------------
__global__ void csr_fill_kernel(const int* __restrict__ src, const int* __restrict__ dst,
                                int* __restrict__ cnt,
                                unsigned short* __restrict__ csr, int E) {
    int e = blockIdx.x * blockDim.x + threadIdx.x;
    if (e < E) {
        int s = src[e];
        int d = dst[e];
        int pos = atomicAdd(&cnt[d], 1);
        csr[(d << 6) + pos] = (unsigned short)s;
    }
}

// fp16 dinv table (incl. dinvh[SENT] = 0 so sentinel edges weigh zero)
__global__ void dinvh_kernel(const int* __restrict__ cnt, __half* __restrict__ dinvh, int n) {
    int i = blockIdx.x * blockDim.x + threadIdx.x;
    if (i < n)  dinvh[i] = __float2half(rsqrtf((float)cnt[i] + 1.0f));
    if (i == n) dinvh[i] = __float2half(0.f);
}

// ---------------------------------------------------------------------------
// Pull-gather (bf16): one wave per dst node, direct buckets, sentinel-padded
// (no bounds checks in inner loop), 16 edges in flight. Degree terms computed
// inline from cnt[d].
// ---------------------------------------------------------------------------
__global__ __launch_bounds__(256) void fused_gather_bf16(
    const __bf16* __restrict__ hb,
    const unsigned short* __restrict__ csr,
    const int* __restrict__ cnt,
    const __half* __restrict__ dinvh,
    __bf16* __restrict__ aggGb,
    __bf16* __restrict__ meanb, int n)
{
    int w = threadIdx.x >> 6;
    int lane = threadIdx.x & 63;
    int d = blockIdx.x * 4 + w;
    if (d >= n) return;
    int c = cnt[d];
    float cf = (float)c;
    float did = rsqrtf(cf + 1.0f);
    float rd  = 1.0f / fmaxf(cf, 1.0f);
    int base = d << 6;
    int iters = (c + 15) >> 4;
    int q  = lane >> 4;
    int c8 = (lane & 15) * 8;

    float aG[8] = {0, 0, 0, 0, 0, 0, 0, 0};
    float aS[8] = {0, 0, 0, 0, 0, 0, 0, 0};

    for (int p = 0; p < iters; p++) {
        int s[4];
        #pragma unroll
        for (int k = 0; k < 4; k++)
            s[k] = csr[base + p * 16 + 4 * k + q];
        uint4 u[4];
        float ds[4];
        #pragma unroll
        for (int k = 0; k < 4; k++) {
            u[k]  = *(const uint4*)(hb + (size_t)s[k] * 128 + c8);
            ds[k] = __half2float(dinvh[s[k]]);
        }
        #pragma unroll
        for (int k = 0; k < 4; k++) {
            float wk = ds[k] * did;   // sentinel: dinvh=0 -> wk=0; row is zero anyway
            float v[8] = { bf_lo(u[k].x), bf_hi(u[k].x), bf_lo(u[k].y), bf_hi(u[k].y),
                           bf_lo(u[k].z), bf_hi(u[k].z), bf_lo(u[k].w), bf_hi(u[k].w) };
            #pragma unroll
            for (int j = 0; j < 8; j++) {
                aG[j] = fmaf(v[j], wk, aG[j]);
                aS[j] += v[j];        // sentinel row is all zeros
            }
        }
    }
    #pragma unroll
    for (int j = 0; j < 8; j++) {
        aG[j] += __shfl_xor(aG[j], 16);
        aG[j] += __shfl_xor(aG[j], 32);
        aS[j] += __shfl_xor(aS[j], 16);
        aS[j] += __shfl_xor(aS[j], 32);
    }
    if (q == 0) {
        uint4 ud = *(const uint4*)(hb + (size_t)d * 128 + c8);
        float vd[8] = { bf_lo(ud.x), bf_hi(ud.x), bf_lo(ud.y), bf_hi(ud.y),
                        bf_lo(ud.z), bf_hi(ud.z), bf_lo(ud.w), bf_hi(ud.w) };
        float sl = did * did;
        union { __bf16 b[8]; uint4 u; } pg, pm;
        #pragma unroll
        for (int j = 0; j < 8; j++) {
            pg.b[j] = (__bf16)fmaf(vd[j], sl, aG[j]);
            pm.b[j] = (__bf16)(aS[j] * rd);
        }
        *(uint4*)(aggGb + (size_t)d * 128 + c8) = pg.u;
        *(uint4*)(meanb + (size_t)d * 128 + c8) = pm.u;
    }
}

// ---------------------------------------------------------------------------
// Pre-MLP: h_bf16 = x_f32 @ pre_w + pre_b, via MFMA; pre_w staged in LDS.
// ---------------------------------------------------------------------------
__global__ __launch_bounds__(256) void pre_gemm_mfma(
    const float* __restrict__ x, const __bf16* __restrict__ Wp0,
    const float* __restrict__ pre_b, __bf16* __restrict__ hb, int n)
{
    __shared__ __bf16 wlds[WPM];               // 32 KB
    const int tid  = threadIdx.x;
    const int w    = tid >> 6;
    const int lane = tid & 63;
    const int r0 = blockIdx.x * 64 + w * 16;
    int rl = r0 + (lane & 15);
    if (rl >= n) rl = n - 1;
    const int kg = lane >> 4;

    {
        uint4* lds4 = (uint4*)wlds;
        const uint4* g = (const uint4*)Wp0;
        #pragma unroll
        for (int it = 0; it < 8; it++)
            lds4[it * 256 + tid] = g[it * 256 + tid];
    }

    f32x4 acc[8];
    #pragma unroll
    for (int cb = 0; cb < 8; cb++) acc[cb] = (f32x4)(0.f);

    v8bf af[4];
    #pragma unroll
    for (int kc = 0; kc < 4; kc++) {
        const float* ap = x + (size_t)rl * 128 + kc * 32 + kg * 8;
        float4 a0 = *(const float4*)ap;
        float4 a1 = *(const float4*)(ap + 4);
        v8bf v;
        v[0] = (__bf16)a0.x; v[1] = (__bf16)a0.y;
        v[2] = (__bf16)a0.z; v[3] = (__bf16)a0.w;
        v[4] = (__bf16)a1.x; v[5] = (__bf16)a1.y;
        v[6] = (__bf16)a1.z; v[7] = (__bf16)a1.w;
        af[kc] = v;
    }
    __syncthreads();

    #pragma unroll
    for (int kc = 0; kc < 4; kc++) {
        #pragma unroll
        for (int cb = 0; cb < 8; cb++) {
            int bo = ((kc * 8 + cb) * 64 + lane) * 8;
            acc[cb] = __builtin_amdgcn_mfma_f32_16x16x32_bf16(
                af[kc], *(const v8bf*)&wlds[bo], acc[cb], 0, 0, 0);
        }
    }
    int cl = lane & 15;
    #pragma unroll
    for (int cb = 0; cb < 8; cb++) {
        float bias = pre_b[cb * 16 + cl];
        #pragma unroll
        for (int j = 0; j < 4; j++) {
            int r = r0 + kg * 4 + j;
            if (r < n) hb[(size_t)r * 128 + cb * 16 + cl] = (__bf16)(acc[cb][j] + bias);
        }
    }
}

// ---------------------------------------------------------------------------
// LAYER GEMM: single K=384 MFMA stream (conv softmax folded into weights),
// B-fragments staged in LDS (two 48KB phases). Then LN blend + act blend.
// ---------------------------------------------------------------------------
__global__ __launch_bounds__(256, 3) void layer_gemm_kernel(
    const __bf16* __restrict__ aggGb, const __bf16* __restrict__ hin,
    const __bf16* __restrict__ meanb,
    const __bf16* __restrict__ WpG, const __bf16* __restrict__ WpS,
    const __bf16* __restrict__ WpN,
    const float* __restrict__ gcn_b,
    const float* __restrict__ lng, const float* __restrict__ lnb,
    const float* __restrict__ anorm, const float* __restrict__ aact,
    const float* __restrict__ aconv,
    __bf16* __restrict__ hout, int n)
{
    __shared__ __bf16 wlds[3 * 16 * 64 * 8];   // 48 KB
    const int tid  = threadIdx.x;
    const int w    = tid >> 6;
    const int lane = tid & 63;
    const int r0 = blockIdx.x * 64 + w * 16;
    int rl = r0 + (lane & 15);
    if (rl >= n) rl = n - 1;
    const int kg = lane >> 4;

    v8bf af[12];
    #pragma unroll
    for (int kc = 0; kc < 4; kc++) {
        size_t ao = (size_t)rl * 128 + kc * 32 + kg * 8;
        af[kc]     = *(const v8bf*)(aggGb + ao);
        af[4 + kc] = *(const v8bf*)(hin   + ao);
        af[8 + kc] = *(const v8bf*)(meanb + ao);
    }

    f32x4 acc[8];
    #pragma unroll
    for (int cb = 0; cb < 8; cb++) acc[cb] = (f32x4)(0.f);

    uint4* lds4 = (uint4*)wlds;

    {
        const uint4* gG = (const uint4*)WpG;
        const uint4* gS = (const uint4*)WpS;
        const uint4* gN = (const uint4*)WpN;
        #pragma unroll
        for (int it = 0; it < 12; it++) {
            int idx = it * 256 + tid;
            int m = idx >> 10;
            int r = idx & 1023;
            const uint4* g = (m == 0) ? gG : (m == 1) ? gS : gN;
            lds4[idx] = g[r];
        }
    }
    __syncthreads();
    #pragma unroll
    for (int kc2 = 0; kc2 < 2; kc2++) {
        #pragma unroll
        for (int cb = 0; cb < 8; cb++) {
            int bo = ((kc2 * 8 + cb) * 64 + lane) * 8;
            acc[cb] = __builtin_amdgcn_mfma_f32_16x16x32_bf16(
                af[kc2], *(const v8bf*)&wlds[bo], acc[cb], 0, 0, 0);
            acc[cb] = __builtin_amdgcn_mfma_f32_16x16x32_bf16(
                af[4 + kc2], *(const v8bf*)&wlds[8192 + bo], acc[cb], 0, 0, 0);
            acc[cb] = __builtin_amdgcn_mfma_f32_16x16x32_bf16(
                af[8 + kc2], *(const v8bf*)&wlds[16384 + bo], acc[cb], 0, 0, 0);
        }
    }
    __syncthreads();

    {
        const uint4* gG = (const uint4*)WpG + 1024;
        const uint4* gS = (const uint4*)WpS + 1024;
        const uint4* gN = (const uint4*)WpN + 1024;
        #pragma unroll
        for (int it = 0; it < 12; it++) {
            int idx = it * 256 + tid;
            int m = idx >> 10;
            int r = idx & 1023;
            const uint4* g = (m == 0) ? gG : (m == 1) ? gS : gN;
            lds4[idx] = g[r];
        }
    }
    __syncthreads();
    #pragma unroll
    for (int kc2 = 0; kc2 < 2; kc2++) {
        #pragma unroll
        for (int cb = 0; cb < 8; cb++) {
            int bo = ((kc2 * 8 + cb) * 64 + lane) * 8;
            acc[cb] = __builtin_amdgcn_mfma_f32_16x16x32_bf16(
                af[2 + kc2], *(const v8bf*)&wlds[bo], acc[cb], 0, 0, 0);
            acc[cb] = __builtin_amdgcn_mfma_f32_16x16x32_bf16(
                af[6 + kc2], *(const v8bf*)&wlds[8192 + bo], acc[cb], 0, 0, 0);
            acc[cb] = __builtin_amdgcn_mfma_f32_16x16x32_bf16(
                af[10 + kc2], *(const v8bf*)&wlds[16384 + bo], acc[cb], 0, 0, 0);
        }
    }

    float c0 = aconv[0], c1 = aconv[1];
    float m = fmaxf(c0, c1);
    float e0 = __expf(c0 - m), e1 = __expf(c1 - m);
    float wc0 = e0 / (e0 + e1);
    float q0 = anorm[0], q1 = anorm[1];
    m = fmaxf(q0, q1);
    e0 = __expf(q0 - m); e1 = __expf(q1 - m);
    float wn0 = e0 / (e0 + e1), wn1 = 1.f - wn0;
    float a0 = aact[0], a1 = aact[1], a2 = aact[2];
    m = fmaxf(fmaxf(a0, a1), a2);
    float f0 = __expf(a0 - m), f1 = __expf(a1 - m), f2 = __expf(a2 - m);
    float fs = 1.f / (f0 + f1 + f2);
    float wa0 = f0 * fs, wa1 = f1 * fs, wa2 = f2 * fs;

    int cl = lane & 15;
    float gbF[8], lg[8], lb[8];
    #pragma unroll
    for (int cb = 0; cb < 8; cb++) {
        int c = cb * 16 + cl;
        gbF[cb] = wc0 * gcn_b[c]; lg[cb] = lng[c]; lb[cb] = lnb[c];
    }

    float s[4] = {0, 0, 0, 0}, s2[4] = {0, 0, 0, 0};
    #pragma unroll
    for (int cb = 0; cb < 8; cb++)
        #pragma unroll
        for (int j = 0; j < 4; j++) {
            float tv = acc[cb][j] + gbF[cb];
            acc[cb][j] = tv;
            s[j] += tv;
            s2[j] = fmaf(tv, tv, s2[j]);
        }
    #pragma unroll
    for (int o = 1; o < 16; o <<= 1)
        #pragma unroll
        for (int j = 0; j < 4; j++) {
            s[j]  += __shfl_xor(s[j], o);
            s2[j] += __shfl_xor(s2[j], o);
        }
    float mu[4], rs[4];
    #pragma unroll
    for (int j = 0; j < 4; j++) {
        mu[j] = s[j] * (1.f / 128.f);
        float var = s2[j] * (1.f / 128.f) - mu[j] * mu[j];
        rs[j] = rsqrtf(var + EPSV);
    }

    #pragma unroll
    for (int j = 0; j < 4; j++) {
        int r = r0 + kg * 4 + j;
        if (r >= n) continue;
        #pragma unroll
        for (int cb = 0; cb < 8; cb++) {
            float tv = acc[cb][j];
            float ln = (tv - mu[j]) * rs[j] * lg[cb] + lb[cb];
            float hv = wn0 * ln + wn1 * tv;
            float rl_ = fmaxf(hv, 0.f);
            float ex2 = __expf(2.f * hv);
            float th = 1.f - 2.f * __builtin_amdgcn_rcpf(ex2 + 1.f);
            float el = hv > 0.f ? hv : __expf(hv) - 1.f;
            float out = wa0 * rl_ + wa1 * th + wa2 * el;
            hout[(size_t)r * 128 + cb * 16 + cl] = (__bf16)out;
        }
    }
}

// ---------------------------------------------------------------------------
// Pooling: sum h1+h2 (bf16), batch sorted -> run-length accumulate.
// ---------------------------------------------------------------------------
__global__ __launch_bounds__(256) void pool_sum_kernel(
    const __bf16* __restrict__ h1, const __bf16* __restrict__ h2,
    const int* __restrict__ batch, float* __restrict__ pooled, int n)
{
    int c2  = (threadIdx.x & 63) * 2;
    int seg = threadIdx.x >> 6;
    int n0  = blockIdx.x * 128 + seg * 32;
    int g_cur = -1;
    float acc0 = 0.f, acc1 = 0.f;
    for (int i = 0; i < 32; i++) {
        int node = n0 + i;
        if (node >= n) break;
        int g = batch[node];
        if (g != g_cur) {
            if (g_cur >= 0) {
                atomicAdd(&pooled[(size_t)g_cur * 128 + c2], acc0);
                atomicAdd(&pooled[(size_t)g_cur * 128 + c2 + 1], acc1);
            }
            g_cur = g; acc0 = 0.f; acc1 = 0.f;
        }
        unsigned u1 = *(const unsigned*)(h1 + (size_t)node * 128 + c2);
        unsigned u2 = *(const unsigned*)(h2 + (size_t)node * 128 + c2);
        acc0 += bf_lo(u1) + bf_lo(u2);
        acc1 += bf_hi(u1) + bf_hi(u2);
    }
    if (g_cur >= 0) {
        atomicAdd(&pooled[(size_t)g_cur * 128 + c2], acc0);
        atomicAdd(&pooled[(size_t)g_cur * 128 + c2 + 1], acc1);
    }
}

__global__ __launch_bounds__(64) void post_gemm_kernel(
    const float* __restrict__ pooled, const float* __restrict__ W,
    const float* __restrict__ b, float* __restrict__ out)
{
    __shared__ float p_s[128];
    int g = blockIdx.x;
    int j = threadIdx.x;
    p_s[j]      = pooled[(size_t)g * 128 + j];
    p_s[j + 64] = pooled[(size_t)g * 128 + 64 + j];
    __syncthreads();
    float acc = b[j];
    #pragma unroll
    for (int k = 0; k < 128; k++)
        acc = fmaf(p_s[k], W[k * 64 + j], acc);
    out[(size_t)g * 64 + j] = acc;
}

// ---------------------------------------------------------------------------
extern "C" void kernel_launch(void* const* d_in, const int* in_sizes, int n_in,
                              void* d_out, int out_size, void* d_ws, size_t ws_size,
                              hipStream_t stream)
{
    const float* x       = (const float*)d_in[0];
    const int*   ei      = (const int*)d_in[1];
    const int*   batch   = (const int*)d_in[2];
    const float* pre_w   = (const float*)d_in[3];
    const float* pre_b   = (const float*)d_in[4];
    const float* post_w  = (const float*)d_in[5];
    const float* post_b  = (const float*)d_in[6];
    const float* gcn_w   = (const float*)d_in[7];
    const float* gcn_b   = (const float*)d_in[8];
    const float* sage_ws = (const float*)d_in[9];
    const float* sage_wn = (const float*)d_in[10];
    const float* ln_g    = (const float*)d_in[11];
    const float* ln_b    = (const float*)d_in[12];
    const float* a_conv  = (const float*)d_in[13];
    const float* a_norm  = (const float*)d_in[14];
    const float* a_act   = (const float*)d_in[15];

    const int* src = ei;
    const int* dst = ei + N_EDGES;

    char* wsp = (char*)d_ws;
    size_t off = 0;
    auto alloc = [&](size_t bytes) {
        char* p = wsp + off;
        off += (bytes + 255) & ~(size_t)255;
        return p;
    };
    // h buffers carry one extra phantom row (index N_NODES, kept zero)
    const size_t NHB = (size_t)(N_NODES + 1) * 128 * sizeof(__bf16);
    __bf16*         hb0    = (__bf16*)alloc(NHB);
    __bf16*         h1b    = (__bf16*)alloc(NHB);
    __bf16*         h2b    = (__bf16*)alloc(NHB);
    __bf16*         aggGb  = (__bf16*)alloc(NHB);
    __bf16*         meanb  = (__bf16*)alloc(NHB);
    __bf16*         Wp     = (__bf16*)alloc((size_t)7 * WPM * sizeof(__bf16));
    __half*         dinvh  = (__half*)alloc((N_NODES + 1) * sizeof(__half));
    int*            cnt    = (int*)alloc(N_NODES * sizeof(int));
    unsigned short* csr    = (unsigned short*)alloc((size_t)N_NODES * CAP * sizeof(unsigned short));
    float*          pooled = (float*)alloc((size_t)G_GRAPHS * 128 * sizeof(float));

    const int GEMM_BLOCKS = (N_NODES + 63) / 64;
    const int GATHER_BLOCKS = (N_NODES + 3) / 4;
    const int SETUP_BLOCKS = (N_NODES * CAP / 8 + 255) / 256;   // 1563

    setup_kernel<<<SETUP_BLOCKS, 256, 0, stream>>>(
        pre_w, gcn_w, sage_ws, sage_wn, a_conv, Wp, cnt, pooled,
        (uint4*)csr,
        (uint4*)(hb0 + (size_t)N_NODES * 128),
        (uint4*)(h1b + (size_t)N_NODES * 128));

    csr_fill_kernel<<<(N_EDGES + 255) / 256, 256, 0, stream>>>(
        src, dst, cnt, csr, N_EDGES);
    dinvh_kernel<<<(N_NODES + 256) / 256, 256, 0, stream>>>(cnt, dinvh, N_NODES);

    pre_gemm_mfma<<<GEMM_BLOCKS, 256, 0, stream>>>(x, Wp, pre_b, hb0, N_NODES);

    const __bf16* hin[2]  = { hb0, h1b };
    __bf16*       hout[2] = { h1b, h2b };
    for (int l = 0; l < 2; l++) {
        fused_gather_bf16<<<GATHER_BLOCKS, 256, 0, stream>>>(
            hin[l], csr, cnt, dinvh, aggGb, meanb, N_NODES);
        layer_gemm_kernel<<<GEMM_BLOCKS, 256, 0, stream>>>(
            aggGb, hin[l], meanb,
            Wp + (size_t)(1 + l) * WPM, Wp + (size_t)(3 + l) * WPM, Wp + (size_t)(5 + l) * WPM,
            gcn_b + l * 128, ln_g + l * 128, ln_b + l * 128,
            a_norm + l * 2, a_act + l * 3, a_conv + l * 2,
            hout[l], N_NODES);
    }

    pool_sum_kernel<<<(N_NODES + 127) / 128, 256, 0, stream>>>(h1b, h2b, batch, pooled, N_NODES);
    post_gemm_kernel<<<G_GRAPHS, 64, 0, stream>>>(pooled, post_w, post_b, (float*)d_out);
}

// Round 13
// 175.595 us; speedup vs baseline: 1.3028x; 1.0509x over previous
//
#include <hip/hip_runtime.h>
#include <hip/hip_fp16.h>
#include <math.h>

#define N_NODES 50000
#define N_EDGES 640000
#define HDIM    128
#define D_OUT   64
#define G_GRAPHS 500
#define EPSV    1e-5f
#define WPM     16384   // elements per packed 128x128 weight matrix
#define CAP     64      // bucket capacity (mean deg 12.8, P(deg>=64)~1e-24)
#define SENT    N_NODES // sentinel src id -> zero row, dinvh[SENT]=0
#define NSHARD  8       // dst shards, aligned with 8 XCDs (blockIdx%8 hint)
#define SHARD_SZ ((N_NODES + NSHARD - 1) / NSHARD)   // 6250

typedef __bf16 v8bf __attribute__((ext_vector_type(8)));
typedef float  f32x4 __attribute__((ext_vector_type(4)));

static __device__ __forceinline__ float bf_lo(unsigned u) {
    union { unsigned x; float f; } c; c.x = u << 16; return c.f;
}
static __device__ __forceinline__ float bf_hi(unsigned u) {
    union { unsigned x; float f; } c; c.x = u & 0xffff0000u; return c.f;
}

// ---------------------------------------------------------------------------
// Setup: zero cnt+pooled, sentinel-fill csr buckets, zero phantom h rows,
// AND pack 7 f32 128x128 weights into bf16 MFMA B-fragment order with
// conv-softmax folded in:
//   m=0: pre_w   m=1,2: wc0[l]*gcn_w[l]  m=3,4: wc1[l]*sage_ws[l]
//   m=5,6: wc1[l]*sage_wn[l]
// ---------------------------------------------------------------------------
__global__ void setup_kernel(const float* __restrict__ pre_w,
                             const float* __restrict__ gcn_w,
                             const float* __restrict__ sws,
                             const float* __restrict__ swn,
                             const float* __restrict__ a_conv,
                             __bf16* __restrict__ Wp,
                             int* __restrict__ cnt,
                             float* __restrict__ pooled,
                             uint4* __restrict__ csr4,
                             uint4* __restrict__ hrow0,
                             uint4* __restrict__ hrow1)
{
    int t = blockIdx.x * blockDim.x + threadIdx.x;
    // sentinel fill: N_NODES*CAP u16 entries = 400000 uint4
    const unsigned sv = ((unsigned)SENT << 16) | (unsigned)SENT;
    if (t < N_NODES * CAP / 8) csr4[t] = make_uint4(sv, sv, sv, sv);
    if (t < N_NODES) cnt[t] = 0;
    if (t < G_GRAPHS * 128) pooled[t] = 0.f;
    if (t < 16) {  // zero phantom row N of hb0 and h1b (256B each)
        hrow0[t] = make_uint4(0, 0, 0, 0);
        hrow1[t] = make_uint4(0, 0, 0, 0);
    }
    if (t >= 7 * 2048) return;
    int m    = t >> 11;
    int r    = t & 2047;
    int lane = r & 63;
    int fb   = r >> 6;           // kc*8 + cb
    int kc   = fb >> 3;
    int cb   = fb & 7;
    const float* W = pre_w;
    float scale = 1.f;
    if (m > 0) {
        int type = (m - 1) >> 1;     // 0=gcn, 1=sage_ws, 2=sage_wn
        int l    = (m - 1) & 1;
        float c0 = a_conv[l * 2], c1 = a_conv[l * 2 + 1];
        float mx = fmaxf(c0, c1);
        float e0 = __expf(c0 - mx), e1 = __expf(c1 - mx);
        float wc0 = e0 / (e0 + e1);
        scale = (type == 0) ? wc0 : (1.f - wc0);
        W = (type == 0) ? gcn_w + (size_t)l * WPM
          : (type == 1) ? sws   + (size_t)l * WPM
                        : swn   + (size_t)l * WPM;
    }
    int k0  = kc * 32 + (lane >> 4) * 8;
    int col = cb * 16 + (lane & 15);
    __bf16* out = Wp + (size_t)m * WPM + ((size_t)fb * 64 + lane) * 8;
    #pragma unroll
    for (int i = 0; i < 8; i++)
        out[i] = (__bf16)(scale * W[(size_t)(k0 + i) * 128 + col]);
}

// ---------------------------------------------------------------------------
// XCD-sharded direct-bucket CSR fill: blocks 8i..8i+7 all process edge chunk
// i; block 8i+s writes only dst-shard s. With round-robin blockIdx->XCD
// dispatch each bucket/cnt line is dirtied by exactly ONE XCD's L2 ->
// minimal partial-line writeback. Correct regardless of the mapping.
// ---------------------------------------------------------------------------
__global__ void csr_fill_kernel(const int* __restrict__ src, const int* __restrict__ dst,
                                int* __restrict__ cnt,
                                unsigned short* __restrict__ csr, int E) {
    int chunk = blockIdx.x >> 3;
    int shard = blockIdx.x & 7;
    int e = chunk * 256 + threadIdx.x;
    if (e >= E) return;
    int d = dst[e];
    if (d / SHARD_SZ != shard) return;
    int s = src[e];
    int pos = atomicAdd(&cnt[d], 1);
    csr[(d << 6) + pos] = (unsigned short)s;
}

// fp16 dinv table (incl. dinvh[SENT] = 0 so sentinel edges weigh zero)
__global__ void dinvh_kernel(const int* __restrict__ cnt, __half* __restrict__ dinvh, int n) {
    int i = blockIdx.x * blockDim.x + threadIdx.x;
    if (i < n)  dinvh[i] = __float2half(rsqrtf((float)cnt[i] + 1.0f));
    if (i == n) dinvh[i] = __float2half(0.f);
}

// ---------------------------------------------------------------------------
// Pull-gather (bf16): one wave per dst node, direct buckets, sentinel-padded
// (no bounds checks in inner loop), 16 edges in flight.
// ---------------------------------------------------------------------------
__global__ __launch_bounds__(256) void fused_gather_bf16(
    const __bf16* __restrict__ hb,
    const unsigned short* __restrict__ csr,
    const int* __restrict__ cnt,
    const __half* __restrict__ dinvh,
    __bf16* __restrict__ aggGb,
    __bf16* __restrict__ meanb, int n)
{
    int w = threadIdx.x >> 6;
    int lane = threadIdx.x & 63;
    int d = blockIdx.x * 4 + w;
    if (d >= n) return;
    int c = cnt[d];
    float cf = (float)c;
    float did = rsqrtf(cf + 1.0f);
    float rd  = 1.0f / fmaxf(cf, 1.0f);
    int base = d << 6;
    int iters = (c + 15) >> 4;
    int q  = lane >> 4;
    int c8 = (lane & 15) * 8;

    float aG[8] = {0, 0, 0, 0, 0, 0, 0, 0};
    float aS[8] = {0, 0, 0, 0, 0, 0, 0, 0};

    for (int p = 0; p < iters; p++) {
        int s[4];
        #pragma unroll
        for (int k = 0; k < 4; k++)
            s[k] = csr[base + p * 16 + 4 * k + q];
        uint4 u[4];
        float ds[4];
        #pragma unroll
        for (int k = 0; k < 4; k++) {
            u[k]  = *(const uint4*)(hb + (size_t)s[k] * 128 + c8);
            ds[k] = __half2float(dinvh[s[k]]);
        }
        #pragma unroll
        for (int k = 0; k < 4; k++) {
            float wk = ds[k] * did;   // sentinel: dinvh=0 -> wk=0; row is zero anyway
            float v[8] = { bf_lo(u[k].x), bf_hi(u[k].x), bf_lo(u[k].y), bf_hi(u[k].y),
                           bf_lo(u[k].z), bf_hi(u[k].z), bf_lo(u[k].w), bf_hi(u[k].w) };
            #pragma unroll
            for (int j = 0; j < 8; j++) {
                aG[j] = fmaf(v[j], wk, aG[j]);
                aS[j] += v[j];        // sentinel row is all zeros
            }
        }
    }
    #pragma unroll
    for (int j = 0; j < 8; j++) {
        aG[j] += __shfl_xor(aG[j], 16);
        aG[j] += __shfl_xor(aG[j], 32);
        aS[j] += __shfl_xor(aS[j], 16);
        aS[j] += __shfl_xor(aS[j], 32);
    }
    if (q == 0) {
        uint4 ud = *(const uint4*)(hb + (size_t)d * 128 + c8);
        float vd[8] = { bf_lo(ud.x), bf_hi(ud.x), bf_lo(ud.y), bf_hi(ud.y),
                        bf_lo(ud.z), bf_hi(ud.z), bf_lo(ud.w), bf_hi(ud.w) };
        float sl = did * did;
        union { __bf16 b[8]; uint4 u; } pg, pm;
        #pragma unroll
        for (int j = 0; j < 8; j++) {
            pg.b[j] = (__bf16)fmaf(vd[j], sl, aG[j]);
            pm.b[j] = (__bf16)(aS[j] * rd);
        }
        *(uint4*)(aggGb + (size_t)d * 128 + c8) = pg.u;
        *(uint4*)(meanb + (size_t)d * 128 + c8) = pm.u;
    }
}

// ---------------------------------------------------------------------------
// Pre-MLP: h_bf16 = x_f32 @ pre_w + pre_b, via MFMA; pre_w staged in LDS.
// ---------------------------------------------------------------------------
__global__ __launch_bounds__(256) void pre_gemm_mfma(
    const float* __restrict__ x, const __bf16* __restrict__ Wp0,
    const float* __restrict__ pre_b, __bf16* __restrict__ hb, int n)
{
    __shared__ __bf16 wlds[WPM];               // 32 KB
    const int tid  = threadIdx.x;
    const int w    = tid >> 6;
    const int lane = tid & 63;
    const int r0 = blockIdx.x * 64 + w * 16;
    int rl = r0 + (lane & 15);
    if (rl >= n) rl = n - 1;
    const int kg = lane >> 4;

    {
        uint4* lds4 = (uint4*)wlds;
        const uint4* g = (const uint4*)Wp0;
        #pragma unroll
        for (int it = 0; it < 8; it++)
            lds4[it * 256 + tid] = g[it * 256 + tid];
    }

    f32x4 acc[8];
    #pragma unroll
    for (int cb = 0; cb < 8; cb++) acc[cb] = (f32x4)(0.f);

    v8bf af[4];
    #pragma unroll
    for (int kc = 0; kc < 4; kc++) {
        const float* ap = x + (size_t)rl * 128 + kc * 32 + kg * 8;
        float4 a0 = *(const float4*)ap;
        float4 a1 = *(const float4*)(ap + 4);
        v8bf v;
        v[0] = (__bf16)a0.x; v[1] = (__bf16)a0.y;
        v[2] = (__bf16)a0.z; v[3] = (__bf16)a0.w;
        v[4] = (__bf16)a1.x; v[5] = (__bf16)a1.y;
        v[6] = (__bf16)a1.z; v[7] = (__bf16)a1.w;
        af[kc] = v;
    }
    __syncthreads();

    #pragma unroll
    for (int kc = 0; kc < 4; kc++) {
        #pragma unroll
        for (int cb = 0; cb < 8; cb++) {
            int bo = ((kc * 8 + cb) * 64 + lane) * 8;
            acc[cb] = __builtin_amdgcn_mfma_f32_16x16x32_bf16(
                af[kc], *(const v8bf*)&wlds[bo], acc[cb], 0, 0, 0);
        }
    }
    int cl = lane & 15;
    #pragma unroll
    for (int cb = 0; cb < 8; cb++) {
        float bias = pre_b[cb * 16 + cl];
        #pragma unroll
        for (int j = 0; j < 4; j++) {
            int r = r0 + kg * 4 + j;
            if (r < n) hb[(size_t)r * 128 + cb * 16 + cl] = (__bf16)(acc[cb][j] + bias);
        }
    }
}

// ---------------------------------------------------------------------------
// LAYER GEMM: single K=384 MFMA stream (conv softmax folded into weights),
// B-fragments staged in LDS (two 48KB phases). Then LN blend + act blend.
// ---------------------------------------------------------------------------
__global__ __launch_bounds__(256, 3) void layer_gemm_kernel(
    const __bf16* __restrict__ aggGb, const __bf16* __restrict__ hin,
    const __bf16* __restrict__ meanb,
    const __bf16* __restrict__ WpG, const __bf16* __restrict__ WpS,
    const __bf16* __restrict__ WpN,
    const float* __restrict__ gcn_b,
    const float* __restrict__ lng, const float* __restrict__ lnb,
    const float* __restrict__ anorm, const float* __restrict__ aact,
    const float* __restrict__ aconv,
    __bf16* __restrict__ hout, int n)
{
    __shared__ __bf16 wlds[3 * 16 * 64 * 8];   // 48 KB
    const int tid  = threadIdx.x;
    const int w    = tid >> 6;
    const int lane = tid & 63;
    const int r0 = blockIdx.x * 64 + w * 16;
    int rl = r0 + (lane & 15);
    if (rl >= n) rl = n - 1;
    const int kg = lane >> 4;

    v8bf af[12];
    #pragma unroll
    for (int kc = 0; kc < 4; kc++) {
        size_t ao = (size_t)rl * 128 + kc * 32 + kg * 8;
        af[kc]     = *(const v8bf*)(aggGb + ao);
        af[4 + kc] = *(const v8bf*)(hin   + ao);
        af[8 + kc] = *(const v8bf*)(meanb + ao);
    }

    f32x4 acc[8];
    #pragma unroll
    for (int cb = 0; cb < 8; cb++) acc[cb] = (f32x4)(0.f);

    uint4* lds4 = (uint4*)wlds;

    {
        const uint4* gG = (const uint4*)WpG;
        const uint4* gS = (const uint4*)WpS;
        const uint4* gN = (const uint4*)WpN;
        #pragma unroll
        for (int it = 0; it < 12; it++) {
            int idx = it * 256 + tid;
            int m = idx >> 10;
            int r = idx & 1023;
            const uint4* g = (m == 0) ? gG : (m == 1) ? gS : gN;
            lds4[idx] = g[r];
        }
    }
    __syncthreads();
    #pragma unroll
    for (int kc2 = 0; kc2 < 2; kc2++) {
        #pragma unroll
        for (int cb = 0; cb < 8; cb++) {
            int bo = ((kc2 * 8 + cb) * 64 + lane) * 8;
            acc[cb] = __builtin_amdgcn_mfma_f32_16x16x32_bf16(
                af[kc2], *(const v8bf*)&wlds[bo], acc[cb], 0, 0, 0);
            acc[cb] = __builtin_amdgcn_mfma_f32_16x16x32_bf16(
                af[4 + kc2], *(const v8bf*)&wlds[8192 + bo], acc[cb], 0, 0, 0);
            acc[cb] = __builtin_amdgcn_mfma_f32_16x16x32_bf16(
                af[8 + kc2], *(const v8bf*)&wlds[16384 + bo], acc[cb], 0, 0, 0);
        }
    }
    __syncthreads();

    {
        const uint4* gG = (const uint4*)WpG + 1024;
        const uint4* gS = (const uint4*)WpS + 1024;
        const uint4* gN = (const uint4*)WpN + 1024;
        #pragma unroll
        for (int it = 0; it < 12; it++) {
            int idx = it * 256 + tid;
            int m = idx >> 10;
            int r = idx & 1023;
            const uint4* g = (m == 0) ? gG : (m == 1) ? gS : gN;
            lds4[idx] = g[r];
        }
    }
    __syncthreads();
    #pragma unroll
    for (int kc2 = 0; kc2 < 2; kc2++) {
        #pragma unroll
        for (int cb = 0; cb < 8; cb++) {
            int bo = ((kc2 * 8 + cb) * 64 + lane) * 8;
            acc[cb] = __builtin_amdgcn_mfma_f32_16x16x32_bf16(
                af[2 + kc2], *(const v8bf*)&wlds[bo], acc[cb], 0, 0, 0);
            acc[cb] = __builtin_amdgcn_mfma_f32_16x16x32_bf16(
                af[6 + kc2], *(const v8bf*)&wlds[8192 + bo], acc[cb], 0, 0, 0);
            acc[cb] = __builtin_amdgcn_mfma_f32_16x16x32_bf16(
                af[10 + kc2], *(const v8bf*)&wlds[16384 + bo], acc[cb], 0, 0, 0);
        }
    }

    float c0 = aconv[0], c1 = aconv[1];
    float m = fmaxf(c0, c1);
    float e0 = __expf(c0 - m), e1 = __expf(c1 - m);
    float wc0 = e0 / (e0 + e1);
    float q0 = anorm[0], q1 = anorm[1];
    m = fmaxf(q0, q1);
    e0 = __expf(q0 - m); e1 = __expf(q1 - m);
    float wn0 = e0 / (e0 + e1), wn1 = 1.f - wn0;
    float a0 = aact[0], a1 = aact[1], a2 = aact[2];
    m = fmaxf(fmaxf(a0, a1), a2);
    float f0 = __expf(a0 - m), f1 = __expf(a1 - m), f2 = __expf(a2 - m);
    float fs = 1.f / (f0 + f1 + f2);
    float wa0 = f0 * fs, wa1 = f1 * fs, wa2 = f2 * fs;

    int cl = lane & 15;
    float gbF[8], lg[8], lb[8];
    #pragma unroll
    for (int cb = 0; cb < 8; cb++) {
        int c = cb * 16 + cl;
        gbF[cb] = wc0 * gcn_b[c]; lg[cb] = lng[c]; lb[cb] = lnb[c];
    }

    float s[4] = {0, 0, 0, 0}, s2[4] = {0, 0, 0, 0};
    #pragma unroll
    for (int cb = 0; cb < 8; cb++)
        #pragma unroll
        for (int j = 0; j < 4; j++) {
            float tv = acc[cb][j] + gbF[cb];
            acc[cb][j] = tv;
            s[j] += tv;
            s2[j] = fmaf(tv, tv, s2[j]);
        }
    #pragma unroll
    for (int o = 1; o < 16; o <<= 1)
        #pragma unroll
        for (int j = 0; j < 4; j++) {
            s[j]  += __shfl_xor(s[j], o);
            s2[j] += __shfl_xor(s2[j], o);
        }
    float mu[4], rs[4];
    #pragma unroll
    for (int j = 0; j < 4; j++) {
        mu[j] = s[j] * (1.f / 128.f);
        float var = s2[j] * (1.f / 128.f) - mu[j] * mu[j];
        rs[j] = rsqrtf(var + EPSV);
    }

    #pragma unroll
    for (int j = 0; j < 4; j++) {
        int r = r0 + kg * 4 + j;
        if (r >= n) continue;
        #pragma unroll
        for (int cb = 0; cb < 8; cb++) {
            float tv = acc[cb][j];
            float ln = (tv - mu[j]) * rs[j] * lg[cb] + lb[cb];
            float hv = wn0 * ln + wn1 * tv;
            float rl_ = fmaxf(hv, 0.f);
            float ex2 = __expf(2.f * hv);
            float th = 1.f - 2.f * __builtin_amdgcn_rcpf(ex2 + 1.f);
            float el = hv > 0.f ? hv : __expf(hv) - 1.f;
            float out = wa0 * rl_ + wa1 * th + wa2 * el;
            hout[(size_t)r * 128 + cb * 16 + cl] = (__bf16)out;
        }
    }
}

// ---------------------------------------------------------------------------
// Pooling: sum h1+h2 (bf16), batch sorted -> run-length accumulate.
// ---------------------------------------------------------------------------
__global__ __launch_bounds__(256) void pool_sum_kernel(
    const __bf16* __restrict__ h1, const __bf16* __restrict__ h2,
    const int* __restrict__ batch, float* __restrict__ pooled, int n)
{
    int c2  = (threadIdx.x & 63) * 2;
    int seg = threadIdx.x >> 6;
    int n0  = blockIdx.x * 128 + seg * 32;
    int g_cur = -1;
    float acc0 = 0.f, acc1 = 0.f;
    for (int i = 0; i < 32; i++) {
        int node = n0 + i;
        if (node >= n) break;
        int g = batch[node];
        if (g != g_cur) {
            if (g_cur >= 0) {
                atomicAdd(&pooled[(size_t)g_cur * 128 + c2], acc0);
                atomicAdd(&pooled[(size_t)g_cur * 128 + c2 + 1], acc1);
            }
            g_cur = g; acc0 = 0.f; acc1 = 0.f;
        }
        unsigned u1 = *(const unsigned*)(h1 + (size_t)node * 128 + c2);
        unsigned u2 = *(const unsigned*)(h2 + (size_t)node * 128 + c2);
        acc0 += bf_lo(u1) + bf_lo(u2);
        acc1 += bf_hi(u1) + bf_hi(u2);
    }
    if (g_cur >= 0) {
        atomicAdd(&pooled[(size_t)g_cur * 128 + c2], acc0);
        atomicAdd(&pooled[(size_t)g_cur * 128 + c2 + 1], acc1);
    }
}

__global__ __launch_bounds__(64) void post_gemm_kernel(
    const float* __restrict__ pooled, const float* __restrict__ W,
    const float* __restrict__ b, float* __restrict__ out)
{
    __shared__ float p_s[128];
    int g = blockIdx.x;
    int j = threadIdx.x;
    p_s[j]      = pooled[(size_t)g * 128 + j];
    p_s[j + 64] = pooled[(size_t)g * 128 + 64 + j];
    __syncthreads();
    float acc = b[j];
    #pragma unroll
    for (int k = 0; k < 128; k++)
        acc = fmaf(p_s[k], W[k * 64 + j], acc);
    out[(size_t)g * 64 + j] = acc;
}

// ---------------------------------------------------------------------------
extern "C" void kernel_launch(void* const* d_in, const int* in_sizes, int n_in,
                              void* d_out, int out_size, void* d_ws, size_t ws_size,
                              hipStream_t stream)
{
    const float* x       = (const float*)d_in[0];
    const int*   ei      = (const int*)d_in[1];
    const int*   batch   = (const int*)d_in[2];
    const float* pre_w   = (const float*)d_in[3];
    const float* pre_b   = (const float*)d_in[4];
    const float* post_w  = (const float*)d_in[5];
    const float* post_b  = (const float*)d_in[6];
    const float* gcn_w   = (const float*)d_in[7];
    const float* gcn_b   = (const float*)d_in[8];
    const float* sage_ws = (const float*)d_in[9];
    const float* sage_wn = (const float*)d_in[10];
    const float* ln_g    = (const float*)d_in[11];
    const float* ln_b    = (const float*)d_in[12];
    const float* a_conv  = (const float*)d_in[13];
    const float* a_norm  = (const float*)d_in[14];
    const float* a_act   = (const float*)d_in[15];

    const int* src = ei;
    const int* dst = ei + N_EDGES;

    char* wsp = (char*)d_ws;
    size_t off = 0;
    auto alloc = [&](size_t bytes) {
        char* p = wsp + off;
        off += (bytes + 255) & ~(size_t)255;
        return p;
    };
    // h buffers carry one extra phantom row (index N_NODES, kept zero)
    const size_t NHB = (size_t)(N_NODES + 1) * 128 * sizeof(__bf16);
    __bf16*         hb0    = (__bf16*)alloc(NHB);
    __bf16*         h1b    = (__bf16*)alloc(NHB);
    __bf16*         h2b    = (__bf16*)alloc(NHB);
    __bf16*         aggGb  = (__bf16*)alloc(NHB);
    __bf16*         meanb  = (__bf16*)alloc(NHB);
    __bf16*         Wp     = (__bf16*)alloc((size_t)7 * WPM * sizeof(__bf16));
    __half*         dinvh  = (__half*)alloc((N_NODES + 1) * sizeof(__half));
    int*            cnt    = (int*)alloc(N_NODES * sizeof(int));
    unsigned short* csr    = (unsigned short*)alloc((size_t)N_NODES * CAP * sizeof(unsigned short));
    float*          pooled = (float*)alloc((size_t)G_GRAPHS * 128 * sizeof(float));

    const int GEMM_BLOCKS = (N_NODES + 63) / 64;
    const int GATHER_BLOCKS = (N_NODES + 3) / 4;
    const int SETUP_BLOCKS = (N_NODES * CAP / 8 + 255) / 256;   // 1563
    const int FILL_BLOCKS  = ((N_EDGES + 255) / 256) * NSHARD;  // 2500*8

    setup_kernel<<<SETUP_BLOCKS, 256, 0, stream>>>(
        pre_w, gcn_w, sage_ws, sage_wn, a_conv, Wp, cnt, pooled,
        (uint4*)csr,
        (uint4*)(hb0 + (size_t)N_NODES * 128),
        (uint4*)(h1b + (size_t)N_NODES * 128));

    csr_fill_kernel<<<FILL_BLOCKS, 256, 0, stream>>>(
        src, dst, cnt, csr, N_EDGES);
    dinvh_kernel<<<(N_NODES + 256) / 256, 256, 0, stream>>>(cnt, dinvh, N_NODES);

    pre_gemm_mfma<<<GEMM_BLOCKS, 256, 0, stream>>>(x, Wp, pre_b, hb0, N_NODES);

    const __bf16* hin[2]  = { hb0, h1b };
    __bf16*       hout[2] = { h1b, h2b };
    for (int l = 0; l < 2; l++) {
        fused_gather_bf16<<<GATHER_BLOCKS, 256, 0, stream>>>(
            hin[l], csr, cnt, dinvh, aggGb, meanb, N_NODES);
        layer_gemm_kernel<<<GEMM_BLOCKS, 256, 0, stream>>>(
            aggGb, hin[l], meanb,
            Wp + (size_t)(1 + l) * WPM, Wp + (size_t)(3 + l) * WPM, Wp + (size_t)(5 + l) * WPM,
            gcn_b + l * 128, ln_g + l * 128, ln_b + l * 128,
            a_norm + l * 2, a_act + l * 3, a_conv + l * 2,
            hout[l], N_NODES);
    }

    pool_sum_kernel<<<(N_NODES + 127) / 128, 256, 0, stream>>>(h1b, h2b, batch, pooled, N_NODES);
    post_gemm_kernel<<<G_GRAPHS, 64, 0, stream>>>(pooled, post_w, post_b, (float*)d_out);
}